// Round 15
// baseline (404.494 us; speedup 1.0000x reference)
//
#include <hip/hip_runtime.h>
#include <hip/hip_fp16.h>
#include <math.h>

#define NND 100000
#define NED 800000
#define NLAY 3
#define BSH 9                      // 512 nodes per bucket
#define NBKT ((NND + 511) / 512)   // 196
#define CAP 8192                   // slack edge capacity per bucket (mean 4096, sigma 64)
#define GB  ((NND + 63) / 64)      // 1563 layer blocks
static constexpr float LNEPS = 1e-5f;

typedef __attribute__((ext_vector_type(8))) short short8;
typedef __attribute__((ext_vector_type(4))) float floatx4;
typedef __attribute__((ext_vector_type(2))) float floatx2;

// fp32 -> bf16 round-to-nearest-even
__device__ __forceinline__ short f2bf(float f) {
    unsigned u = __float_as_uint(f);
    u += 0x7fffu + ((u >> 16) & 1u);
    return (short)(u >> 16);
}
__device__ __forceinline__ float bf2f(short s) {
    return __uint_as_float(((unsigned)(unsigned short)s) << 16);
}

// unpack 8 consecutive halfs (16B) into fp32
__device__ __forceinline__ void load_h8(const __half* p, float* f) {
    uint4 v = *(const uint4*)p;
    unsigned a[4] = {v.x, v.y, v.z, v.w};
#pragma unroll
    for (int k = 0; k < 4; k++) {
        __half2 h = *(__half2*)&a[k];
        float2 g = __half22float2(h);
        f[2 * k] = g.x; f[2 * k + 1] = g.y;
    }
}

// unpack 16 consecutive fp8 e4m3 (16B) into fp32 via HW pk-cvt
__device__ __forceinline__ void load_f8x16(const unsigned char* p, float* f) {
    uint4 v = *(const uint4*)p;
    unsigned a[4] = {v.x, v.y, v.z, v.w};
#pragma unroll
    for (int k = 0; k < 4; k++) {
        floatx2 lo = __builtin_amdgcn_cvt_pk_f32_fp8(a[k], false);
        floatx2 hi = __builtin_amdgcn_cvt_pk_f32_fp8(a[k], true);
        f[4 * k + 0] = lo[0]; f[4 * k + 1] = lo[1];
        f[4 * k + 2] = hi[0]; f[4 * k + 3] = hi[1];
    }
}
__device__ __forceinline__ unsigned char f32_to_fp8(float v) {
    int r = __builtin_amdgcn_cvt_pk_fp8_f32(v, v, 0, false);
    return (unsigned char)(r & 0xff);
}

// ---------------- init: bucket tails to slack bases ----------------
__global__ void k_init(int* __restrict__ gtail) {
    int gt = blockIdx.x * blockDim.x + threadIdx.x;
    if (gt < NBKT) gtail[gt] = gt * CAP;
}

// ---------------- bin edges by bucket into slack-capacity tmp (packed tgt<<32|src) ----------------
__global__ __launch_bounds__(256) void k_bscatter(const int2* __restrict__ e, int* __restrict__ gtail,
                                                  long long* __restrict__ tmp) {
    __shared__ int cnt[NBKT], chunk[NBKT], cur[NBKT];
    const int T = 2048;
    int ntile = (NED + T - 1) / T;
    for (int tile = blockIdx.x; tile < ntile; tile += gridDim.x) {
        int base = tile * T;
        int t = threadIdx.x;
        for (int i = t; i < NBKT; i += 256) { cnt[i] = 0; cur[i] = 0; }
        __syncthreads();
        int2 ed[8]; int bk[8];
#pragma unroll
        for (int i = 0; i < 8; i++) {
            int idx = base + i * 256 + t;
            if (idx < NED) {
                ed[i] = e[idx];
                bk[i] = ((unsigned)ed[i].y) >> BSH;
                atomicAdd(&cnt[bk[i]], 1);
            } else bk[i] = -1;
        }
        __syncthreads();
        for (int i = t; i < NBKT; i += 256) if (cnt[i]) chunk[i] = atomicAdd(&gtail[i], cnt[i]);
        __syncthreads();
#pragma unroll
        for (int i = 0; i < 8; i++) {
            if (bk[i] >= 0) {
                int r = atomicAdd(&cur[bk[i]], 1);
                tmp[(size_t)chunk[bk[i]] + r] =
                    ((long long)(unsigned)ed[i].y << 32) | (unsigned)ed[i].x;
            }
        }
        __syncthreads();
    }
}

// ---------------- per-bucket CSR finish: rowb (begin) + degv (degree) + srcs ----------------
__global__ __launch_bounds__(512) void k_bfinish(const long long* __restrict__ tmp, const int* __restrict__ gtail,
                                                 int* __restrict__ rowb, int* __restrict__ degv,
                                                 int* __restrict__ srcs) {
    __shared__ int ld[512];
    __shared__ int lcur[512];
    int b = blockIdx.x, t = threadIdx.x;
    int node0 = b << BSH;
    int nn = min(512, NND - node0);
    int ebase = b * CAP, eend = gtail[b];
    ld[t] = 0;
    __syncthreads();
    for (int i = ebase + t; i < eend; i += 512) {
        int tgt = (int)(tmp[i] >> 32);
        atomicAdd(&ld[tgt - node0], 1);
    }
    __syncthreads();
    int v = ld[t];
    for (int off = 1; off < 512; off <<= 1) {
        int u = (t >= off) ? ld[t - off] : 0;
        __syncthreads();
        ld[t] += u;
        __syncthreads();
    }
    int exc = ld[t] - v;
    if (t < nn) { rowb[node0 + t] = ebase + exc; degv[node0 + t] = v; }
    lcur[t] = exc;
    __syncthreads();
    for (int i = ebase + t; i < eend; i += 512) {
        long long pk = tmp[i];
        int tgt = (int)(pk >> 32);
        int src = (int)(pk & 0xffffffffll);
        int p = atomicAdd(&lcur[tgt - node0], 1);
        srcs[ebase + p] = src;
    }
}

// ---------------- prep: pre-swizzle weights into MFMA B-fragment layout (bf16) ----------------
__global__ void k_prep(const float* __restrict__ msg_w, const float* __restrict__ upd_w,
                       short* __restrict__ wmsg, short* __restrict__ wupd) {
    int t = blockIdx.x * blockDim.x + threadIdx.x;
    if (t >= 2 * NLAY * 8192) return;
    int which = t / (NLAY * 8192);
    int e = t % (NLAY * 8192);
    int l = e >> 13, idx = e & 8191;
    int j = idx & 7, lane = (idx >> 3) & 63, hi = idx >> 9;
    int lm = lane & 15, quad = lane >> 4;
    if (which == 0) {
        int ks = hi & 1, nt = hi >> 1;
        int n = nt * 16 + lm, k = ks * 32 + quad * 8 + j;
        float v = (n < 64) ? msg_w[(size_t)l * 8192 + k * 64 + n]
                           : msg_w[(size_t)l * 8192 + (64 + k) * 64 + (n - 64)];
        wmsg[e] = f2bf(v);
    } else {
        int ks = hi & 3, nt = hi >> 2;
        int n = nt * 16 + lm, k = ks * 32 + quad * 8 + j;
        wupd[e] = f2bf(upd_w[(size_t)l * 8192 + k * 64 + n]);
    }
}

// ---------------- layer-0 P(fp8)/Q(fp16) + embed fused, per-wave staging (barrier-free) ----------------
__global__ __launch_bounds__(256) void k_pq(const int* __restrict__ ty, const float* __restrict__ tab,
                                            const short* __restrict__ wb, const float* __restrict__ bg,
                                            unsigned char* __restrict__ P8, __half* __restrict__ Q16,
                                            short* __restrict__ x16) {
    __shared__ unsigned char outs[64 * 272];   // per node: 64B P fp8 | 128B Q half | 80B pad
    int wv = threadIdx.x >> 6, lane = threadIdx.x & 63;
    int lm = lane & 15, quad = lane >> 4;
    int nbase = blockIdx.x * 64;
    int m = nbase + wv * 16 + lm;
    short8 a[2];
    if (m < NND) {
        const float* tr = tab + ty[m] * 64;
#pragma unroll
        for (int ks = 0; ks < 2; ks++) {
            float4 v0 = *(const float4*)(tr + ks * 32 + quad * 8);
            float4 v1 = *(const float4*)(tr + ks * 32 + quad * 8 + 4);
            short8 av;
            av[0] = f2bf(v0.x); av[1] = f2bf(v0.y); av[2] = f2bf(v0.z); av[3] = f2bf(v0.w);
            av[4] = f2bf(v1.x); av[5] = f2bf(v1.y); av[6] = f2bf(v1.z); av[7] = f2bf(v1.w);
            a[ks] = av;
            *(short8*)(x16 + (size_t)m * 64 + ks * 32 + quad * 8) = av;   // embed fused
        }
    } else {
#pragma unroll
        for (int ks = 0; ks < 2; ks++) { short8 z; for (int j = 0; j < 8; j++) z[j] = 0; a[ks] = z; }
    }
    floatx4 acc[8];
#pragma unroll
    for (int nt = 0; nt < 8; nt++) acc[nt] = (floatx4){0.f, 0.f, 0.f, 0.f};
#pragma unroll
    for (int nt = 0; nt < 8; nt++) {
        short8 b0 = *(const short8*)(wb + (size_t)((nt * 2 + 0) * 64 + lane) * 8);
        short8 b1 = *(const short8*)(wb + (size_t)((nt * 2 + 1) * 64 + lane) * 8);
        acc[nt] = __builtin_amdgcn_mfma_f32_16x16x32_bf16(a[0], b0, acc[nt], 0, 0, 0);
        acc[nt] = __builtin_amdgcn_mfma_f32_16x16x32_bf16(a[1], b1, acc[nt], 0, 0, 0);
    }
    float bq[4];
#pragma unroll
    for (int nt = 0; nt < 4; nt++) bq[nt] = bg[nt * 16 + lm];
#pragma unroll
    for (int reg = 0; reg < 4; reg++) {
        int rown = wv * 16 + quad * 4 + reg;
        unsigned char* rb = outs + rown * 272;
#pragma unroll
        for (int nt = 0; nt < 4; nt++)
            rb[nt * 16 + lm] = f32_to_fp8(acc[nt][reg]);
#pragma unroll
        for (int nt = 4; nt < 8; nt++)
            *(__half*)(rb + 64 + (((nt - 4) * 16 + lm) << 1)) = __float2half(acc[nt][reg] + bq[nt - 4]);
    }
    // per-wave store of own 16 rows (same-wave LDS ordering, no barrier)
#pragma unroll
    for (int pass = 0; pass < 3; pass++) {
        int idx = pass * 64 + lane;          // 0..191 = 16 nodes x 12 segs
        int ndl = (idx * 171) >> 11;         // idx/12
        int seg = idx - ndl * 12;
        int rown = wv * 16 + ndl;
        int gn = nbase + rown;
        if (gn < NND) {
            int off = (seg < 4) ? seg * 16 : 64 + (seg - 4) * 16;
            uint4 v = *(const uint4*)(outs + rown * 272 + off);
            if (seg < 4) *(uint4*)(P8 + (size_t)gn * 64 + seg * 16) = v;
            else *(uint4*)((char*)Q16 + (size_t)gn * 128 + (seg - 4) * 16) = v;
        }
    }
}

// ---------------- fused layer: barrier-free wave-owned tiles; fp8 P; full occupancy (8 waves/EU) ----------------
__global__ __launch_bounds__(256, 8) void k_aggupd(short* __restrict__ x16, const unsigned char* __restrict__ P8,
                                                   const __half* __restrict__ Q16,
                                                   const int* __restrict__ rowb, const int* __restrict__ degv,
                                                   const int* __restrict__ srcs,
                                                   const short* __restrict__ wu, const float* __restrict__ ub,
                                                   const float* __restrict__ lg, const float* __restrict__ lb,
                                                   const short* __restrict__ wm, const float* __restrict__ bgn,
                                                   unsigned char* __restrict__ Pout, __half* __restrict__ Qout,
                                                   float* __restrict__ pscratch, int last) {
    __shared__ float aggs[64 * 68];            // 17408 B; reused as byte-staging (stride 272) in phase 3
    __shared__ float redsum[64];
    __shared__ unsigned redmax[64];
    int t = threadIdx.x, w = t >> 6, lane = t & 63;

    if (last) {
        if (t < 64) redsum[t] = 0.f;
        else if (t < 128) redmax[t - 64] = 0u;
        __syncthreads();
    }

    // ---- phase 1: gather (lane = node w*16+(lane>>2), feats (lane&3)*16..+15; fp8 P) ----
    {
        int ln = lane >> 2, fq = lane & 3, c0 = fq * 16;
        int bn = w * 16 + ln;
        int wid = blockIdx.x * 64 + bn;
        float acc[16];
#pragma unroll
        for (int k = 0; k < 16; k++) acc[k] = 0.f;
        if (wid < NND) {
            int beg = rowb[wid], dg = degv[wid], end = beg + dg;
            float qv[16];
            load_h8(Q16 + (size_t)wid * 64 + c0, qv);
            load_h8(Q16 + (size_t)wid * 64 + c0 + 8, qv + 8);
            int e = beg;
            int n0 = 0, n1 = 0, n2 = 0, n3 = 0;
            if (e + 4 <= end) { n0 = srcs[e]; n1 = srcs[e + 1]; n2 = srcs[e + 2]; n3 = srcs[e + 3]; }
            while (e + 4 <= end) {
                int c0s = n0, c1s = n1, c2s = n2, c3s = n3;
                int en = e + 4;
                if (en + 4 <= end) { n0 = srcs[en]; n1 = srcs[en + 1]; n2 = srcs[en + 2]; n3 = srcs[en + 3]; }
                float f0[16], f1[16], f2[16], f3[16];
                load_f8x16(P8 + (size_t)c0s * 64 + c0, f0);
                load_f8x16(P8 + (size_t)c1s * 64 + c0, f1);
                load_f8x16(P8 + (size_t)c2s * 64 + c0, f2);
                load_f8x16(P8 + (size_t)c3s * 64 + c0, f3);
#pragma unroll
                for (int k = 0; k < 16; k++) {
                    acc[k] += fmaxf(f0[k] + qv[k], 0.f) + fmaxf(f1[k] + qv[k], 0.f);
                    acc[k] += fmaxf(f2[k] + qv[k], 0.f) + fmaxf(f3[k] + qv[k], 0.f);
                }
                e = en;
            }
            for (; e < end; e++) {
                int s = srcs[e];
                float f0[16];
                load_f8x16(P8 + (size_t)s * 64 + c0, f0);
#pragma unroll
                for (int k = 0; k < 16; k++) acc[k] += fmaxf(f0[k] + qv[k], 0.f);
            }
            float inv = 1.f / fmaxf((float)dg, 1.f);
#pragma unroll
            for (int s4 = 0; s4 < 4; s4++)
                *(float4*)(aggs + bn * 68 + c0 + s4 * 4) =
                    make_float4(acc[s4 * 4] * inv, acc[s4 * 4 + 1] * inv,
                                acc[s4 * 4 + 2] * inv, acc[s4 * 4 + 3] * inv);
        } else {
#pragma unroll
            for (int s4 = 0; s4 < 4; s4++)
                *(float4*)(aggs + bn * 68 + c0 + s4 * 4) = make_float4(0.f, 0.f, 0.f, 0.f);
        }
    }
    // no barrier: all LDS deps are same-wave (HW-ordered)

    int lm = lane & 15, quad = lane >> 4;
    int m = blockIdx.x * 64 + w * 16 + lm;
    int bm = w * 16 + lm;

    // ---- phase 2: upd MFMA + LN (own tile) ----
    short8 a[4];
#pragma unroll
    for (int ks = 0; ks < 2; ks++) {
        if (m < NND) a[ks] = *(const short8*)(x16 + (size_t)m * 64 + ks * 32 + quad * 8);
        else { short8 z; for (int j = 0; j < 8; j++) z[j] = 0; a[ks] = z; }
    }
#pragma unroll
    for (int ks = 2; ks < 4; ks++) {
        const float* p = aggs + bm * 68 + (ks - 2) * 32 + quad * 8;
        float4 v0 = *(const float4*)p;
        float4 v1 = *(const float4*)(p + 4);
        float xv[8] = {v0.x, v0.y, v0.z, v0.w, v1.x, v1.y, v1.z, v1.w};
        short8 av;
#pragma unroll
        for (int j = 0; j < 8; j++) av[j] = f2bf(xv[j]);
        a[ks] = av;
    }
    floatx4 acc4[4];
#pragma unroll
    for (int nt = 0; nt < 4; nt++) acc4[nt] = (floatx4){0.f, 0.f, 0.f, 0.f};
#pragma unroll
    for (int nt = 0; nt < 4; nt++) {
#pragma unroll
        for (int ks = 0; ks < 4; ks++) {
            short8 b = *(const short8*)(wu + (size_t)((nt * 4 + ks) * 64 + lane) * 8);
            acc4[nt] = __builtin_amdgcn_mfma_f32_16x16x32_bf16(a[ks], b, acc4[nt], 0, 0, 0);
        }
    }
    float ubv[4], lgv[4], lbv[4];
#pragma unroll
    for (int nt = 0; nt < 4; nt++) {
        int col = nt * 16 + lm;
        ubv[nt] = ub[col]; lgv[nt] = lg[col]; lbv[nt] = lb[col];
    }
    float csum[4] = {0.f, 0.f, 0.f, 0.f};
    float cmax[4] = {-3.402823466e38f, -3.402823466e38f, -3.402823466e38f, -3.402823466e38f};
#pragma unroll
    for (int reg = 0; reg < 4; reg++) {
        int rown = w * 16 + quad * 4 + reg;
        int gn = blockIdx.x * 64 + rown;
        bool ok = gn < NND;
        float h[4];
#pragma unroll
        for (int nt = 0; nt < 4; nt++) {
            float xv = ok ? bf2f(x16[(size_t)gn * 64 + nt * 16 + lm]) : 0.f;
            float u = fmaxf(acc4[nt][reg] + ubv[nt], 0.f);
            h[nt] = u + xv;
        }
        float s1 = h[0] + h[1] + h[2] + h[3];
        float s2 = h[0] * h[0] + h[1] * h[1] + h[2] * h[2] + h[3] * h[3];
#pragma unroll
        for (int off = 1; off < 16; off *= 2) {
            s1 += __shfl_xor(s1, off);
            s2 += __shfl_xor(s2, off);
        }
        float mu = s1 * (1.f / 64.f);
        float var = s2 * (1.f / 64.f) - mu * mu;
        float rs = rsqrtf(var + LNEPS);
#pragma unroll
        for (int nt = 0; nt < 4; nt++) {
            float res = (h[nt] - mu) * rs * lgv[nt] + lbv[nt];
            if (!last) {
                if (ok) x16[(size_t)gn * 64 + nt * 16 + lm] = f2bf(res);
                aggs[rown * 68 + nt * 16 + lm] = res;   // new-x for phase 3 (own tile rows)
            } else if (ok) {
                csum[nt] += res;
                cmax[nt] = fmaxf(cmax[nt], res);
            }
        }
    }

    if (last) {
        // ---- folded final reduce: quad-combine, LDS stage, NON-ATOMIC per-block partials ----
#pragma unroll
        for (int nt = 0; nt < 4; nt++) {
            csum[nt] += __shfl_xor(csum[nt], 16);
            csum[nt] += __shfl_xor(csum[nt], 32);
            cmax[nt] = fmaxf(cmax[nt], __shfl_xor(cmax[nt], 16));
            cmax[nt] = fmaxf(cmax[nt], __shfl_xor(cmax[nt], 32));
        }
        if (quad == 0) {
#pragma unroll
            for (int nt = 0; nt < 4; nt++) {
                atomicAdd(&redsum[nt * 16 + lm], csum[nt]);
                unsigned b = __float_as_uint(cmax[nt]);
                unsigned enc = (b & 0x80000000u) ? ~b : (b | 0x80000000u);
                atomicMax(&redmax[nt * 16 + lm], enc);
            }
        }
        __syncthreads();
        float* ps = pscratch + (size_t)blockIdx.x * 128;
        if (t < 64) {
            ps[t] = redsum[t];
        } else if (t < 128) {
            unsigned u = redmax[t - 64];
            unsigned b = (u & 0x80000000u) ? (u & 0x7fffffffu) : ~u;
            ps[t] = __uint_as_float(b);
        }
        return;
    }

    // ---- phase 3: next-layer P(fp8)/Q(fp16) for own tile (same wave, no barrier) ----
    {
        unsigned char* bs = (unsigned char*)aggs;    // byte view, row stride 272
        short8 na[2];
#pragma unroll
        for (int ks = 0; ks < 2; ks++) {
            const float* p = aggs + bm * 68 + ks * 32 + quad * 8;
            float4 v0 = *(const float4*)p;
            float4 v1 = *(const float4*)(p + 4);
            float xv[8] = {v0.x, v0.y, v0.z, v0.w, v1.x, v1.y, v1.z, v1.w};
            short8 av;
#pragma unroll
            for (int j = 0; j < 8; j++) av[j] = f2bf(xv[j]);
            na[ks] = av;
        }
        floatx4 c8[8];
#pragma unroll
        for (int nt = 0; nt < 8; nt++) c8[nt] = (floatx4){0.f, 0.f, 0.f, 0.f};
#pragma unroll
        for (int nt = 0; nt < 8; nt++) {
            short8 b0 = *(const short8*)(wm + (size_t)((nt * 2 + 0) * 64 + lane) * 8);
            short8 b1 = *(const short8*)(wm + (size_t)((nt * 2 + 1) * 64 + lane) * 8);
            c8[nt] = __builtin_amdgcn_mfma_f32_16x16x32_bf16(na[0], b0, c8[nt], 0, 0, 0);
            c8[nt] = __builtin_amdgcn_mfma_f32_16x16x32_bf16(na[1], b1, c8[nt], 0, 0, 0);
        }
        float bq[4];
#pragma unroll
        for (int nt = 0; nt < 4; nt++) bq[nt] = bgn[nt * 16 + lm];
#pragma unroll
        for (int reg = 0; reg < 4; reg++) {
            int rown = w * 16 + quad * 4 + reg;
            unsigned char* rb = bs + rown * 272;
#pragma unroll
            for (int nt = 0; nt < 4; nt++)
                rb[nt * 16 + lm] = f32_to_fp8(c8[nt][reg]);
#pragma unroll
            for (int nt = 4; nt < 8; nt++)
                *(__half*)(rb + 64 + (((nt - 4) * 16 + lm) << 1)) = __float2half(c8[nt][reg] + bq[nt - 4]);
        }
#pragma unroll
        for (int pass = 0; pass < 3; pass++) {
            int idx = pass * 64 + lane;          // 0..191 = 16 nodes x 12 segs
            int ndl = (idx * 171) >> 11;         // idx/12
            int seg = idx - ndl * 12;
            int rown = w * 16 + ndl;
            int gn = blockIdx.x * 64 + rown;
            if (gn < NND) {
                int off = (seg < 4) ? seg * 16 : 64 + (seg - 4) * 16;
                uint4 v = *(const uint4*)(bs + rown * 272 + off);
                if (seg < 4) *(uint4*)(Pout + (size_t)gn * 64 + seg * 16) = v;
                else *(uint4*)((char*)Qout + (size_t)gn * 128 + (seg - 4) * 16) = v;
            }
        }
    }
}

// ---------------- final: 128 blocks, block c reduces column c over GB block-partials ----------------
__global__ __launch_bounds__(256) void k_fin(const float* __restrict__ pscratch, float* __restrict__ out) {
    __shared__ float sm[256];
    int b = blockIdx.x;      // 0..127: 0-63 sum columns, 64-127 max columns
    int t = threadIdx.x;
    bool issum = b < 64;
    float v = issum ? 0.f : -3.402823466e38f;
    for (int i = t; i < GB; i += 256) {
        float x = pscratch[(size_t)i * 128 + b];
        v = issum ? (v + x) : fmaxf(v, x);
    }
    sm[t] = v; __syncthreads();
    for (int off = 128; off > 0; off >>= 1) {
        if (t < off) sm[t] = issum ? (sm[t] + sm[t + off]) : fmaxf(sm[t], sm[t + off]);
        __syncthreads();
    }
    if (t == 0) out[b] = issum ? sm[0] * (1.f / (float)NND) : sm[0];
}

extern "C" void kernel_launch(void* const* d_in, const int* in_sizes, int n_in,
                              void* d_out, int out_size, void* d_ws, size_t ws_size,
                              hipStream_t stream) {
    const int* ty      = (const int*)d_in[0];
    const int* ed      = (const int*)d_in[1];
    const float* tab   = (const float*)d_in[2];
    const float* msg_w = (const float*)d_in[3];
    const float* msg_b = (const float*)d_in[4];
    const float* upd_w = (const float*)d_in[5];
    const float* upd_b = (const float*)d_in[6];
    const float* ln_g  = (const float*)d_in[7];
    const float* ln_b  = (const float*)d_in[8];
    float* out = (float*)d_out;

    char* w = (char*)d_ws;
    auto alloc = [&](size_t sz) { char* p = w; w += (sz + 255) & ~(size_t)255; return p; };
    short* x16         = (short*)alloc((size_t)NND * 64 * 2);
    unsigned char* P0  = (unsigned char*)alloc((size_t)NND * 64);
    unsigned char* P1  = (unsigned char*)alloc((size_t)NND * 64);
    __half* Q0         = (__half*)alloc((size_t)NND * 64 * 2);
    __half* Q1         = (__half*)alloc((size_t)NND * 64 * 2);
    long long* tmp     = (long long*)alloc((size_t)NBKT * CAP * 8);
    int* srcs          = (int*)alloc((size_t)NBKT * CAP * 4);
    int* rowb          = (int*)alloc((size_t)NND * 4);
    int* degv          = (int*)alloc((size_t)NND * 4);
    int* gtail         = (int*)alloc(256 * 4);
    float* pscratch    = (float*)alloc((size_t)GB * 128 * 4);
    short* wmsg        = (short*)alloc((size_t)NLAY * 8192 * 2);
    short* wupd        = (short*)alloc((size_t)NLAY * 8192 * 2);

    k_init<<<1, 256, 0, stream>>>(gtail);
    k_prep<<<(2 * NLAY * 8192 + 255) / 256, 256, 0, stream>>>(msg_w, upd_w, wmsg, wupd);
    k_bscatter<<<(NED + 2047) / 2048, 256, 0, stream>>>((const int2*)ed, gtail, tmp);
    k_bfinish<<<NBKT, 512, 0, stream>>>(tmp, gtail, rowb, degv, srcs);

    k_pq<<<GB, 256, 0, stream>>>(ty, tab, wmsg, msg_b, P0, Q0, x16);

    k_aggupd<<<GB, 256, 0, stream>>>(x16, P0, Q0, rowb, degv, srcs,
                                     wupd + 0 * 8192, upd_b + 0, ln_g + 0, ln_b + 0,
                                     wmsg + 1 * 8192, msg_b + 64, P1, Q1, pscratch, 0);
    k_aggupd<<<GB, 256, 0, stream>>>(x16, P1, Q1, rowb, degv, srcs,
                                     wupd + 1 * 8192, upd_b + 64, ln_g + 64, ln_b + 64,
                                     wmsg + 2 * 8192, msg_b + 128, P0, Q0, pscratch, 0);
    k_aggupd<<<GB, 256, 0, stream>>>(x16, P0, Q0, rowb, degv, srcs,
                                     wupd + 2 * 8192, upd_b + 128, ln_g + 128, ln_b + 128,
                                     wmsg + 2 * 8192, msg_b + 128, P1, Q1, pscratch, 1);

    k_fin<<<128, 256, 0, stream>>>(pscratch, out);
}

// Round 16
// 344.715 us; speedup vs baseline: 1.1734x; 1.1734x over previous
//
#include <hip/hip_runtime.h>
#include <hip/hip_fp16.h>
#include <math.h>

#define NND 100000
#define NED 800000
#define NLAY 3
#define BSH 9                      // 512 nodes per bucket
#define NBKT ((NND + 511) / 512)   // 196
#define CAP 8192                   // slack edge capacity per bucket (mean 4096, sigma 64)
#define GB  ((NND + 63) / 64)      // 1563 layer blocks
static constexpr float LNEPS = 1e-5f;

typedef __attribute__((ext_vector_type(8))) short short8;
typedef __attribute__((ext_vector_type(4))) float floatx4;
typedef __attribute__((ext_vector_type(2))) float floatx2;

// fp32 -> bf16 round-to-nearest-even
__device__ __forceinline__ short f2bf(float f) {
    unsigned u = __float_as_uint(f);
    u += 0x7fffu + ((u >> 16) & 1u);
    return (short)(u >> 16);
}
__device__ __forceinline__ float bf2f(short s) {
    return __uint_as_float(((unsigned)(unsigned short)s) << 16);
}

// unpack 8 consecutive halfs (16B) into fp32
__device__ __forceinline__ void load_h8(const __half* p, float* f) {
    uint4 v = *(const uint4*)p;
    unsigned a[4] = {v.x, v.y, v.z, v.w};
#pragma unroll
    for (int k = 0; k < 4; k++) {
        __half2 h = *(__half2*)&a[k];
        float2 g = __half22float2(h);
        f[2 * k] = g.x; f[2 * k + 1] = g.y;
    }
}

// unpack 16 consecutive fp8 e4m3 (16B) into fp32 via HW pk-cvt
__device__ __forceinline__ void load_f8x16(const unsigned char* p, float* f) {
    uint4 v = *(const uint4*)p;
    unsigned a[4] = {v.x, v.y, v.z, v.w};
#pragma unroll
    for (int k = 0; k < 4; k++) {
        floatx2 lo = __builtin_amdgcn_cvt_pk_f32_fp8(a[k], false);
        floatx2 hi = __builtin_amdgcn_cvt_pk_f32_fp8(a[k], true);
        f[4 * k + 0] = lo[0]; f[4 * k + 1] = lo[1];
        f[4 * k + 2] = hi[0]; f[4 * k + 3] = hi[1];
    }
}
__device__ __forceinline__ unsigned char f32_to_fp8(float v) {
    int r = __builtin_amdgcn_cvt_pk_fp8_f32(v, v, 0, false);
    return (unsigned char)(r & 0xff);
}

// ---------------- init: bucket tails to slack bases ----------------
__global__ void k_init(int* __restrict__ gtail) {
    int gt = blockIdx.x * blockDim.x + threadIdx.x;
    if (gt < NBKT) gtail[gt] = gt * CAP;
}

// ---------------- bin edges by bucket into slack-capacity tmp (packed tgt<<32|src) ----------------
__global__ __launch_bounds__(256) void k_bscatter(const int2* __restrict__ e, int* __restrict__ gtail,
                                                  long long* __restrict__ tmp) {
    __shared__ int cnt[NBKT], chunk[NBKT], cur[NBKT];
    const int T = 2048;
    int ntile = (NED + T - 1) / T;
    for (int tile = blockIdx.x; tile < ntile; tile += gridDim.x) {
        int base = tile * T;
        int t = threadIdx.x;
        for (int i = t; i < NBKT; i += 256) { cnt[i] = 0; cur[i] = 0; }
        __syncthreads();
        int2 ed[8]; int bk[8];
#pragma unroll
        for (int i = 0; i < 8; i++) {
            int idx = base + i * 256 + t;
            if (idx < NED) {
                ed[i] = e[idx];
                bk[i] = ((unsigned)ed[i].y) >> BSH;
                atomicAdd(&cnt[bk[i]], 1);
            } else bk[i] = -1;
        }
        __syncthreads();
        for (int i = t; i < NBKT; i += 256) if (cnt[i]) chunk[i] = atomicAdd(&gtail[i], cnt[i]);
        __syncthreads();
#pragma unroll
        for (int i = 0; i < 8; i++) {
            if (bk[i] >= 0) {
                int r = atomicAdd(&cur[bk[i]], 1);
                tmp[(size_t)chunk[bk[i]] + r] =
                    ((long long)(unsigned)ed[i].y << 32) | (unsigned)ed[i].x;
            }
        }
        __syncthreads();
    }
}

// ---------------- per-bucket CSR finish: rowb (begin) + degv (degree) + srcs ----------------
__global__ __launch_bounds__(512) void k_bfinish(const long long* __restrict__ tmp, const int* __restrict__ gtail,
                                                 int* __restrict__ rowb, int* __restrict__ degv,
                                                 int* __restrict__ srcs) {
    __shared__ int ld[512];
    __shared__ int lcur[512];
    int b = blockIdx.x, t = threadIdx.x;
    int node0 = b << BSH;
    int nn = min(512, NND - node0);
    int ebase = b * CAP, eend = gtail[b];
    ld[t] = 0;
    __syncthreads();
    for (int i = ebase + t; i < eend; i += 512) {
        int tgt = (int)(tmp[i] >> 32);
        atomicAdd(&ld[tgt - node0], 1);
    }
    __syncthreads();
    int v = ld[t];
    for (int off = 1; off < 512; off <<= 1) {
        int u = (t >= off) ? ld[t - off] : 0;
        __syncthreads();
        ld[t] += u;
        __syncthreads();
    }
    int exc = ld[t] - v;
    if (t < nn) { rowb[node0 + t] = ebase + exc; degv[node0 + t] = v; }
    lcur[t] = exc;
    __syncthreads();
    for (int i = ebase + t; i < eend; i += 512) {
        long long pk = tmp[i];
        int tgt = (int)(pk >> 32);
        int src = (int)(pk & 0xffffffffll);
        int p = atomicAdd(&lcur[tgt - node0], 1);
        srcs[ebase + p] = src;
    }
}

// ---------------- prep: pre-swizzle weights into MFMA B-fragment layout (bf16) ----------------
__global__ void k_prep(const float* __restrict__ msg_w, const float* __restrict__ upd_w,
                       short* __restrict__ wmsg, short* __restrict__ wupd) {
    int t = blockIdx.x * blockDim.x + threadIdx.x;
    if (t >= 2 * NLAY * 8192) return;
    int which = t / (NLAY * 8192);
    int e = t % (NLAY * 8192);
    int l = e >> 13, idx = e & 8191;
    int j = idx & 7, lane = (idx >> 3) & 63, hi = idx >> 9;
    int lm = lane & 15, quad = lane >> 4;
    if (which == 0) {
        int ks = hi & 1, nt = hi >> 1;
        int n = nt * 16 + lm, k = ks * 32 + quad * 8 + j;
        float v = (n < 64) ? msg_w[(size_t)l * 8192 + k * 64 + n]
                           : msg_w[(size_t)l * 8192 + (64 + k) * 64 + (n - 64)];
        wmsg[e] = f2bf(v);
    } else {
        int ks = hi & 3, nt = hi >> 2;
        int n = nt * 16 + lm, k = ks * 32 + quad * 8 + j;
        wupd[e] = f2bf(upd_w[(size_t)l * 8192 + k * 64 + n]);
    }
}

// ---------------- layer-0 P(fp8)/Q(fp16) + embed fused, per-wave staging (barrier-free) ----------------
__global__ __launch_bounds__(256) void k_pq(const int* __restrict__ ty, const float* __restrict__ tab,
                                            const short* __restrict__ wb, const float* __restrict__ bg,
                                            unsigned char* __restrict__ P8, __half* __restrict__ Q16,
                                            short* __restrict__ x16) {
    __shared__ unsigned char outs[64 * 272];   // per node: 64B P fp8 | 128B Q half | 80B pad
    int wv = threadIdx.x >> 6, lane = threadIdx.x & 63;
    int lm = lane & 15, quad = lane >> 4;
    int nbase = blockIdx.x * 64;
    int m = nbase + wv * 16 + lm;
    short8 a[2];
    if (m < NND) {
        const float* tr = tab + ty[m] * 64;
#pragma unroll
        for (int ks = 0; ks < 2; ks++) {
            float4 v0 = *(const float4*)(tr + ks * 32 + quad * 8);
            float4 v1 = *(const float4*)(tr + ks * 32 + quad * 8 + 4);
            short8 av;
            av[0] = f2bf(v0.x); av[1] = f2bf(v0.y); av[2] = f2bf(v0.z); av[3] = f2bf(v0.w);
            av[4] = f2bf(v1.x); av[5] = f2bf(v1.y); av[6] = f2bf(v1.z); av[7] = f2bf(v1.w);
            a[ks] = av;
            *(short8*)(x16 + (size_t)m * 64 + ks * 32 + quad * 8) = av;   // embed fused
        }
    } else {
#pragma unroll
        for (int ks = 0; ks < 2; ks++) { short8 z; for (int j = 0; j < 8; j++) z[j] = 0; a[ks] = z; }
    }
    floatx4 acc[8];
#pragma unroll
    for (int nt = 0; nt < 8; nt++) acc[nt] = (floatx4){0.f, 0.f, 0.f, 0.f};
#pragma unroll
    for (int nt = 0; nt < 8; nt++) {
        short8 b0 = *(const short8*)(wb + (size_t)((nt * 2 + 0) * 64 + lane) * 8);
        short8 b1 = *(const short8*)(wb + (size_t)((nt * 2 + 1) * 64 + lane) * 8);
        acc[nt] = __builtin_amdgcn_mfma_f32_16x16x32_bf16(a[0], b0, acc[nt], 0, 0, 0);
        acc[nt] = __builtin_amdgcn_mfma_f32_16x16x32_bf16(a[1], b1, acc[nt], 0, 0, 0);
    }
    float bq[4];
#pragma unroll
    for (int nt = 0; nt < 4; nt++) bq[nt] = bg[nt * 16 + lm];
#pragma unroll
    for (int reg = 0; reg < 4; reg++) {
        int rown = wv * 16 + quad * 4 + reg;
        unsigned char* rb = outs + rown * 272;
#pragma unroll
        for (int nt = 0; nt < 4; nt++)
            rb[nt * 16 + lm] = f32_to_fp8(acc[nt][reg]);
#pragma unroll
        for (int nt = 4; nt < 8; nt++)
            *(__half*)(rb + 64 + (((nt - 4) * 16 + lm) << 1)) = __float2half(acc[nt][reg] + bq[nt - 4]);
    }
    // per-wave store of own 16 rows (same-wave LDS ordering, no barrier)
#pragma unroll
    for (int pass = 0; pass < 3; pass++) {
        int idx = pass * 64 + lane;          // 0..191 = 16 nodes x 12 segs
        int ndl = (idx * 171) >> 11;         // idx/12
        int seg = idx - ndl * 12;
        int rown = wv * 16 + ndl;
        int gn = nbase + rown;
        if (gn < NND) {
            int off = (seg < 4) ? seg * 16 : 64 + (seg - 4) * 16;
            uint4 v = *(const uint4*)(outs + rown * 272 + off);
            if (seg < 4) *(uint4*)(P8 + (size_t)gn * 64 + seg * 16) = v;
            else *(uint4*)((char*)Q16 + (size_t)gn * 128 + (seg - 4) * 16) = v;
        }
    }
}

// ---------------- fused layer: barrier-free wave-owned tiles; fp8 P; 6 waves/EU (VGPR cap ~80 > natural 60) ----------------
__global__ __launch_bounds__(256, 6) void k_aggupd(short* __restrict__ x16, const unsigned char* __restrict__ P8,
                                                   const __half* __restrict__ Q16,
                                                   const int* __restrict__ rowb, const int* __restrict__ degv,
                                                   const int* __restrict__ srcs,
                                                   const short* __restrict__ wu, const float* __restrict__ ub,
                                                   const float* __restrict__ lg, const float* __restrict__ lb,
                                                   const short* __restrict__ wm, const float* __restrict__ bgn,
                                                   unsigned char* __restrict__ Pout, __half* __restrict__ Qout,
                                                   float* __restrict__ pscratch, int last) {
    __shared__ float aggs[64 * 68];            // 17408 B; reused as byte-staging (stride 272) in phase 3
    __shared__ float redsum[64];
    __shared__ unsigned redmax[64];
    int t = threadIdx.x, w = t >> 6, lane = t & 63;

    if (last) {
        if (t < 64) redsum[t] = 0.f;
        else if (t < 128) redmax[t - 64] = 0u;
        __syncthreads();
    }

    // ---- phase 1: gather (lane = node w*16+(lane>>2), feats (lane&3)*16..+15; fp8 P) ----
    {
        int ln = lane >> 2, fq = lane & 3, c0 = fq * 16;
        int bn = w * 16 + ln;
        int wid = blockIdx.x * 64 + bn;
        float acc[16];
#pragma unroll
        for (int k = 0; k < 16; k++) acc[k] = 0.f;
        if (wid < NND) {
            int beg = rowb[wid], dg = degv[wid], end = beg + dg;
            float qv[16];
            load_h8(Q16 + (size_t)wid * 64 + c0, qv);
            load_h8(Q16 + (size_t)wid * 64 + c0 + 8, qv + 8);
            int e = beg;
            int n0 = 0, n1 = 0, n2 = 0, n3 = 0;
            if (e + 4 <= end) { n0 = srcs[e]; n1 = srcs[e + 1]; n2 = srcs[e + 2]; n3 = srcs[e + 3]; }
            while (e + 4 <= end) {
                int c0s = n0, c1s = n1, c2s = n2, c3s = n3;
                int en = e + 4;
                if (en + 4 <= end) { n0 = srcs[en]; n1 = srcs[en + 1]; n2 = srcs[en + 2]; n3 = srcs[en + 3]; }
                float f0[16], f1[16], f2[16], f3[16];
                load_f8x16(P8 + (size_t)c0s * 64 + c0, f0);
                load_f8x16(P8 + (size_t)c1s * 64 + c0, f1);
                load_f8x16(P8 + (size_t)c2s * 64 + c0, f2);
                load_f8x16(P8 + (size_t)c3s * 64 + c0, f3);
#pragma unroll
                for (int k = 0; k < 16; k++) {
                    acc[k] += fmaxf(f0[k] + qv[k], 0.f) + fmaxf(f1[k] + qv[k], 0.f);
                    acc[k] += fmaxf(f2[k] + qv[k], 0.f) + fmaxf(f3[k] + qv[k], 0.f);
                }
                e = en;
            }
            for (; e < end; e++) {
                int s = srcs[e];
                float f0[16];
                load_f8x16(P8 + (size_t)s * 64 + c0, f0);
#pragma unroll
                for (int k = 0; k < 16; k++) acc[k] += fmaxf(f0[k] + qv[k], 0.f);
            }
            float inv = 1.f / fmaxf((float)dg, 1.f);
#pragma unroll
            for (int s4 = 0; s4 < 4; s4++)
                *(float4*)(aggs + bn * 68 + c0 + s4 * 4) =
                    make_float4(acc[s4 * 4] * inv, acc[s4 * 4 + 1] * inv,
                                acc[s4 * 4 + 2] * inv, acc[s4 * 4 + 3] * inv);
        } else {
#pragma unroll
            for (int s4 = 0; s4 < 4; s4++)
                *(float4*)(aggs + bn * 68 + c0 + s4 * 4) = make_float4(0.f, 0.f, 0.f, 0.f);
        }
    }
    // no barrier: all LDS deps are same-wave (HW-ordered)

    int lm = lane & 15, quad = lane >> 4;
    int m = blockIdx.x * 64 + w * 16 + lm;
    int bm = w * 16 + lm;

    // ---- phase 2: upd MFMA + LN (own tile) ----
    short8 a[4];
#pragma unroll
    for (int ks = 0; ks < 2; ks++) {
        if (m < NND) a[ks] = *(const short8*)(x16 + (size_t)m * 64 + ks * 32 + quad * 8);
        else { short8 z; for (int j = 0; j < 8; j++) z[j] = 0; a[ks] = z; }
    }
#pragma unroll
    for (int ks = 2; ks < 4; ks++) {
        const float* p = aggs + bm * 68 + (ks - 2) * 32 + quad * 8;
        float4 v0 = *(const float4*)p;
        float4 v1 = *(const float4*)(p + 4);
        float xv[8] = {v0.x, v0.y, v0.z, v0.w, v1.x, v1.y, v1.z, v1.w};
        short8 av;
#pragma unroll
        for (int j = 0; j < 8; j++) av[j] = f2bf(xv[j]);
        a[ks] = av;
    }
    floatx4 acc4[4];
#pragma unroll
    for (int nt = 0; nt < 4; nt++) acc4[nt] = (floatx4){0.f, 0.f, 0.f, 0.f};
#pragma unroll
    for (int nt = 0; nt < 4; nt++) {
#pragma unroll
        for (int ks = 0; ks < 4; ks++) {
            short8 b = *(const short8*)(wu + (size_t)((nt * 4 + ks) * 64 + lane) * 8);
            acc4[nt] = __builtin_amdgcn_mfma_f32_16x16x32_bf16(a[ks], b, acc4[nt], 0, 0, 0);
        }
    }
    float ubv[4], lgv[4], lbv[4];
#pragma unroll
    for (int nt = 0; nt < 4; nt++) {
        int col = nt * 16 + lm;
        ubv[nt] = ub[col]; lgv[nt] = lg[col]; lbv[nt] = lb[col];
    }
    float csum[4] = {0.f, 0.f, 0.f, 0.f};
    float cmax[4] = {-3.402823466e38f, -3.402823466e38f, -3.402823466e38f, -3.402823466e38f};
#pragma unroll
    for (int reg = 0; reg < 4; reg++) {
        int rown = w * 16 + quad * 4 + reg;
        int gn = blockIdx.x * 64 + rown;
        bool ok = gn < NND;
        float h[4];
#pragma unroll
        for (int nt = 0; nt < 4; nt++) {
            float xv = ok ? bf2f(x16[(size_t)gn * 64 + nt * 16 + lm]) : 0.f;
            float u = fmaxf(acc4[nt][reg] + ubv[nt], 0.f);
            h[nt] = u + xv;
        }
        float s1 = h[0] + h[1] + h[2] + h[3];
        float s2 = h[0] * h[0] + h[1] * h[1] + h[2] * h[2] + h[3] * h[3];
#pragma unroll
        for (int off = 1; off < 16; off *= 2) {
            s1 += __shfl_xor(s1, off);
            s2 += __shfl_xor(s2, off);
        }
        float mu = s1 * (1.f / 64.f);
        float var = s2 * (1.f / 64.f) - mu * mu;
        float rs = rsqrtf(var + LNEPS);
#pragma unroll
        for (int nt = 0; nt < 4; nt++) {
            float res = (h[nt] - mu) * rs * lgv[nt] + lbv[nt];
            if (!last) {
                if (ok) x16[(size_t)gn * 64 + nt * 16 + lm] = f2bf(res);
                aggs[rown * 68 + nt * 16 + lm] = res;   // new-x for phase 3 (own tile rows)
            } else if (ok) {
                csum[nt] += res;
                cmax[nt] = fmaxf(cmax[nt], res);
            }
        }
    }

    if (last) {
        // ---- folded final reduce: quad-combine, LDS stage, NON-ATOMIC per-block partials ----
#pragma unroll
        for (int nt = 0; nt < 4; nt++) {
            csum[nt] += __shfl_xor(csum[nt], 16);
            csum[nt] += __shfl_xor(csum[nt], 32);
            cmax[nt] = fmaxf(cmax[nt], __shfl_xor(cmax[nt], 16));
            cmax[nt] = fmaxf(cmax[nt], __shfl_xor(cmax[nt], 32));
        }
        if (quad == 0) {
#pragma unroll
            for (int nt = 0; nt < 4; nt++) {
                atomicAdd(&redsum[nt * 16 + lm], csum[nt]);
                unsigned b = __float_as_uint(cmax[nt]);
                unsigned enc = (b & 0x80000000u) ? ~b : (b | 0x80000000u);
                atomicMax(&redmax[nt * 16 + lm], enc);
            }
        }
        __syncthreads();
        float* ps = pscratch + (size_t)blockIdx.x * 128;
        if (t < 64) {
            ps[t] = redsum[t];
        } else if (t < 128) {
            unsigned u = redmax[t - 64];
            unsigned b = (u & 0x80000000u) ? (u & 0x7fffffffu) : ~u;
            ps[t] = __uint_as_float(b);
        }
        return;
    }

    // ---- phase 3: next-layer P(fp8)/Q(fp16) for own tile (same wave, no barrier) ----
    {
        unsigned char* bs = (unsigned char*)aggs;    // byte view, row stride 272
        short8 na[2];
#pragma unroll
        for (int ks = 0; ks < 2; ks++) {
            const float* p = aggs + bm * 68 + ks * 32 + quad * 8;
            float4 v0 = *(const float4*)p;
            float4 v1 = *(const float4*)(p + 4);
            float xv[8] = {v0.x, v0.y, v0.z, v0.w, v1.x, v1.y, v1.z, v1.w};
            short8 av;
#pragma unroll
            for (int j = 0; j < 8; j++) av[j] = f2bf(xv[j]);
            na[ks] = av;
        }
        floatx4 c8[8];
#pragma unroll
        for (int nt = 0; nt < 8; nt++) c8[nt] = (floatx4){0.f, 0.f, 0.f, 0.f};
#pragma unroll
        for (int nt = 0; nt < 8; nt++) {
            short8 b0 = *(const short8*)(wm + (size_t)((nt * 2 + 0) * 64 + lane) * 8);
            short8 b1 = *(const short8*)(wm + (size_t)((nt * 2 + 1) * 64 + lane) * 8);
            c8[nt] = __builtin_amdgcn_mfma_f32_16x16x32_bf16(na[0], b0, c8[nt], 0, 0, 0);
            c8[nt] = __builtin_amdgcn_mfma_f32_16x16x32_bf16(na[1], b1, c8[nt], 0, 0, 0);
        }
        float bq[4];
#pragma unroll
        for (int nt = 0; nt < 4; nt++) bq[nt] = bgn[nt * 16 + lm];
#pragma unroll
        for (int reg = 0; reg < 4; reg++) {
            int rown = w * 16 + quad * 4 + reg;
            unsigned char* rb = bs + rown * 272;
#pragma unroll
            for (int nt = 0; nt < 4; nt++)
                rb[nt * 16 + lm] = f32_to_fp8(c8[nt][reg]);
#pragma unroll
            for (int nt = 4; nt < 8; nt++)
                *(__half*)(rb + 64 + (((nt - 4) * 16 + lm) << 1)) = __float2half(c8[nt][reg] + bq[nt - 4]);
        }
#pragma unroll
        for (int pass = 0; pass < 3; pass++) {
            int idx = pass * 64 + lane;          // 0..191 = 16 nodes x 12 segs
            int ndl = (idx * 171) >> 11;         // idx/12
            int seg = idx - ndl * 12;
            int rown = w * 16 + ndl;
            int gn = blockIdx.x * 64 + rown;
            if (gn < NND) {
                int off = (seg < 4) ? seg * 16 : 64 + (seg - 4) * 16;
                uint4 v = *(const uint4*)(bs + rown * 272 + off);
                if (seg < 4) *(uint4*)(Pout + (size_t)gn * 64 + seg * 16) = v;
                else *(uint4*)((char*)Qout + (size_t)gn * 128 + (seg - 4) * 16) = v;
            }
        }
    }
}

// ---------------- final: 128 blocks, block c reduces column c over GB block-partials ----------------
__global__ __launch_bounds__(256) void k_fin(const float* __restrict__ pscratch, float* __restrict__ out) {
    __shared__ float sm[256];
    int b = blockIdx.x;      // 0..127: 0-63 sum columns, 64-127 max columns
    int t = threadIdx.x;
    bool issum = b < 64;
    float v = issum ? 0.f : -3.402823466e38f;
    for (int i = t; i < GB; i += 256) {
        float x = pscratch[(size_t)i * 128 + b];
        v = issum ? (v + x) : fmaxf(v, x);
    }
    sm[t] = v; __syncthreads();
    for (int off = 128; off > 0; off >>= 1) {
        if (t < off) sm[t] = issum ? (sm[t] + sm[t + off]) : fmaxf(sm[t], sm[t + off]);
        __syncthreads();
    }
    if (t == 0) out[b] = issum ? sm[0] * (1.f / (float)NND) : sm[0];
}

extern "C" void kernel_launch(void* const* d_in, const int* in_sizes, int n_in,
                              void* d_out, int out_size, void* d_ws, size_t ws_size,
                              hipStream_t stream) {
    const int* ty      = (const int*)d_in[0];
    const int* ed      = (const int*)d_in[1];
    const float* tab   = (const float*)d_in[2];
    const float* msg_w = (const float*)d_in[3];
    const float* msg_b = (const float*)d_in[4];
    const float* upd_w = (const float*)d_in[5];
    const float* upd_b = (const float*)d_in[6];
    const float* ln_g  = (const float*)d_in[7];
    const float* ln_b  = (const float*)d_in[8];
    float* out = (float*)d_out;

    char* w = (char*)d_ws;
    auto alloc = [&](size_t sz) { char* p = w; w += (sz + 255) & ~(size_t)255; return p; };
    short* x16         = (short*)alloc((size_t)NND * 64 * 2);
    unsigned char* P0  = (unsigned char*)alloc((size_t)NND * 64);
    unsigned char* P1  = (unsigned char*)alloc((size_t)NND * 64);
    __half* Q0         = (__half*)alloc((size_t)NND * 64 * 2);
    __half* Q1         = (__half*)alloc((size_t)NND * 64 * 2);
    long long* tmp     = (long long*)alloc((size_t)NBKT * CAP * 8);
    int* srcs          = (int*)alloc((size_t)NBKT * CAP * 4);
    int* rowb          = (int*)alloc((size_t)NND * 4);
    int* degv          = (int*)alloc((size_t)NND * 4);
    int* gtail         = (int*)alloc(256 * 4);
    float* pscratch    = (float*)alloc((size_t)GB * 128 * 4);
    short* wmsg        = (short*)alloc((size_t)NLAY * 8192 * 2);
    short* wupd        = (short*)alloc((size_t)NLAY * 8192 * 2);

    k_init<<<1, 256, 0, stream>>>(gtail);
    k_prep<<<(2 * NLAY * 8192 + 255) / 256, 256, 0, stream>>>(msg_w, upd_w, wmsg, wupd);
    k_bscatter<<<(NED + 2047) / 2048, 256, 0, stream>>>((const int2*)ed, gtail, tmp);
    k_bfinish<<<NBKT, 512, 0, stream>>>(tmp, gtail, rowb, degv, srcs);

    k_pq<<<GB, 256, 0, stream>>>(ty, tab, wmsg, msg_b, P0, Q0, x16);

    k_aggupd<<<GB, 256, 0, stream>>>(x16, P0, Q0, rowb, degv, srcs,
                                     wupd + 0 * 8192, upd_b + 0, ln_g + 0, ln_b + 0,
                                     wmsg + 1 * 8192, msg_b + 64, P1, Q1, pscratch, 0);
    k_aggupd<<<GB, 256, 0, stream>>>(x16, P1, Q1, rowb, degv, srcs,
                                     wupd + 1 * 8192, upd_b + 64, ln_g + 64, ln_b + 64,
                                     wmsg + 2 * 8192, msg_b + 128, P0, Q0, pscratch, 0);
    k_aggupd<<<GB, 256, 0, stream>>>(x16, P0, Q0, rowb, degv, srcs,
                                     wupd + 2 * 8192, upd_b + 128, ln_g + 128, ln_b + 128,
                                     wmsg + 2 * 8192, msg_b + 128, P1, Q1, pscratch, 1);

    k_fin<<<128, 256, 0, stream>>>(pscratch, out);
}

// Round 17
// 226.736 us; speedup vs baseline: 1.7840x; 1.5203x over previous
//
#include <hip/hip_runtime.h>
#include <hip/hip_fp16.h>
#include <math.h>

#define NND 100000
#define NED 800000
#define NLAY 3
#define BSH 9                      // 512 nodes per bucket
#define NBKT ((NND + 511) / 512)   // 196
#define CAP 8192                   // slack edge capacity per bucket (mean 4096, sigma 64)
#define GB  ((NND + 63) / 64)      // 1563 layer blocks
static constexpr float LNEPS = 1e-5f;

typedef __attribute__((ext_vector_type(8))) short short8;
typedef __attribute__((ext_vector_type(4))) float floatx4;
typedef __attribute__((ext_vector_type(2))) float floatx2;

// fp32 -> bf16 round-to-nearest-even
__device__ __forceinline__ short f2bf(float f) {
    unsigned u = __float_as_uint(f);
    u += 0x7fffu + ((u >> 16) & 1u);
    return (short)(u >> 16);
}
__device__ __forceinline__ float bf2f(short s) {
    return __uint_as_float(((unsigned)(unsigned short)s) << 16);
}

// unpack 8 consecutive halfs (16B) into fp32
__device__ __forceinline__ void load_h8(const __half* p, float* f) {
    uint4 v = *(const uint4*)p;
    unsigned a[4] = {v.x, v.y, v.z, v.w};
#pragma unroll
    for (int k = 0; k < 4; k++) {
        __half2 h = *(__half2*)&a[k];
        float2 g = __half22float2(h);
        f[2 * k] = g.x; f[2 * k + 1] = g.y;
    }
}

// unpack 16 consecutive fp8 e4m3 (16B) into fp32 via HW pk-cvt
__device__ __forceinline__ void load_f8x16(const unsigned char* p, float* f) {
    uint4 v = *(const uint4*)p;
    unsigned a[4] = {v.x, v.y, v.z, v.w};
#pragma unroll
    for (int k = 0; k < 4; k++) {
        floatx2 lo = __builtin_amdgcn_cvt_pk_f32_fp8(a[k], false);
        floatx2 hi = __builtin_amdgcn_cvt_pk_f32_fp8(a[k], true);
        f[4 * k + 0] = lo[0]; f[4 * k + 1] = lo[1];
        f[4 * k + 2] = hi[0]; f[4 * k + 3] = hi[1];
    }
}
__device__ __forceinline__ unsigned char f32_to_fp8(float v) {
    int r = __builtin_amdgcn_cvt_pk_fp8_f32(v, v, 0, false);
    return (unsigned char)(r & 0xff);
}

// ---------------- init: bucket tails to slack bases ----------------
__global__ void k_init(int* __restrict__ gtail) {
    int gt = blockIdx.x * blockDim.x + threadIdx.x;
    if (gt < NBKT) gtail[gt] = gt * CAP;
}

// ---------------- bin edges by bucket into slack-capacity tmp (packed tgt<<32|src) ----------------
__global__ __launch_bounds__(256) void k_bscatter(const int2* __restrict__ e, int* __restrict__ gtail,
                                                  long long* __restrict__ tmp) {
    __shared__ int cnt[NBKT], chunk[NBKT], cur[NBKT];
    const int T = 2048;
    int ntile = (NED + T - 1) / T;
    for (int tile = blockIdx.x; tile < ntile; tile += gridDim.x) {
        int base = tile * T;
        int t = threadIdx.x;
        for (int i = t; i < NBKT; i += 256) { cnt[i] = 0; cur[i] = 0; }
        __syncthreads();
        int2 ed[8]; int bk[8];
#pragma unroll
        for (int i = 0; i < 8; i++) {
            int idx = base + i * 256 + t;
            if (idx < NED) {
                ed[i] = e[idx];
                bk[i] = ((unsigned)ed[i].y) >> BSH;
                atomicAdd(&cnt[bk[i]], 1);
            } else bk[i] = -1;
        }
        __syncthreads();
        for (int i = t; i < NBKT; i += 256) if (cnt[i]) chunk[i] = atomicAdd(&gtail[i], cnt[i]);
        __syncthreads();
#pragma unroll
        for (int i = 0; i < 8; i++) {
            if (bk[i] >= 0) {
                int r = atomicAdd(&cur[bk[i]], 1);
                tmp[(size_t)chunk[bk[i]] + r] =
                    ((long long)(unsigned)ed[i].y << 32) | (unsigned)ed[i].x;
            }
        }
        __syncthreads();
    }
}

// ---------------- per-bucket CSR finish: rowb (begin) + degv (degree) + srcs ----------------
__global__ __launch_bounds__(512) void k_bfinish(const long long* __restrict__ tmp, const int* __restrict__ gtail,
                                                 int* __restrict__ rowb, int* __restrict__ degv,
                                                 int* __restrict__ srcs) {
    __shared__ int ld[512];
    __shared__ int lcur[512];
    int b = blockIdx.x, t = threadIdx.x;
    int node0 = b << BSH;
    int nn = min(512, NND - node0);
    int ebase = b * CAP, eend = gtail[b];
    ld[t] = 0;
    __syncthreads();
    for (int i = ebase + t; i < eend; i += 512) {
        int tgt = (int)(tmp[i] >> 32);
        atomicAdd(&ld[tgt - node0], 1);
    }
    __syncthreads();
    int v = ld[t];
    for (int off = 1; off < 512; off <<= 1) {
        int u = (t >= off) ? ld[t - off] : 0;
        __syncthreads();
        ld[t] += u;
        __syncthreads();
    }
    int exc = ld[t] - v;
    if (t < nn) { rowb[node0 + t] = ebase + exc; degv[node0 + t] = v; }
    lcur[t] = exc;
    __syncthreads();
    for (int i = ebase + t; i < eend; i += 512) {
        long long pk = tmp[i];
        int tgt = (int)(pk >> 32);
        int src = (int)(pk & 0xffffffffll);
        int p = atomicAdd(&lcur[tgt - node0], 1);
        srcs[ebase + p] = src;
    }
}

// ---------------- prep: pre-swizzle weights into MFMA B-fragment layout (bf16) ----------------
__global__ void k_prep(const float* __restrict__ msg_w, const float* __restrict__ upd_w,
                       short* __restrict__ wmsg, short* __restrict__ wupd) {
    int t = blockIdx.x * blockDim.x + threadIdx.x;
    if (t >= 2 * NLAY * 8192) return;
    int which = t / (NLAY * 8192);
    int e = t % (NLAY * 8192);
    int l = e >> 13, idx = e & 8191;
    int j = idx & 7, lane = (idx >> 3) & 63, hi = idx >> 9;
    int lm = lane & 15, quad = lane >> 4;
    if (which == 0) {
        int ks = hi & 1, nt = hi >> 1;
        int n = nt * 16 + lm, k = ks * 32 + quad * 8 + j;
        float v = (n < 64) ? msg_w[(size_t)l * 8192 + k * 64 + n]
                           : msg_w[(size_t)l * 8192 + (64 + k) * 64 + (n - 64)];
        wmsg[e] = f2bf(v);
    } else {
        int ks = hi & 3, nt = hi >> 2;
        int n = nt * 16 + lm, k = ks * 32 + quad * 8 + j;
        wupd[e] = f2bf(upd_w[(size_t)l * 8192 + k * 64 + n]);
    }
}

// ---------------- layer-0 P(fp8)/Q(fp16) + embed fused, per-wave staging (barrier-free) ----------------
__global__ __launch_bounds__(256) void k_pq(const int* __restrict__ ty, const float* __restrict__ tab,
                                            const short* __restrict__ wb, const float* __restrict__ bg,
                                            unsigned char* __restrict__ P8, __half* __restrict__ Q16,
                                            short* __restrict__ x16) {
    __shared__ unsigned char outs[64 * 272];   // per node: 64B P fp8 | 128B Q half | 80B pad
    int wv = threadIdx.x >> 6, lane = threadIdx.x & 63;
    int lm = lane & 15, quad = lane >> 4;
    int nbase = blockIdx.x * 64;
    int m = nbase + wv * 16 + lm;
    short8 a[2];
    if (m < NND) {
        const float* tr = tab + ty[m] * 64;
#pragma unroll
        for (int ks = 0; ks < 2; ks++) {
            float4 v0 = *(const float4*)(tr + ks * 32 + quad * 8);
            float4 v1 = *(const float4*)(tr + ks * 32 + quad * 8 + 4);
            short8 av;
            av[0] = f2bf(v0.x); av[1] = f2bf(v0.y); av[2] = f2bf(v0.z); av[3] = f2bf(v0.w);
            av[4] = f2bf(v1.x); av[5] = f2bf(v1.y); av[6] = f2bf(v1.z); av[7] = f2bf(v1.w);
            a[ks] = av;
            *(short8*)(x16 + (size_t)m * 64 + ks * 32 + quad * 8) = av;   // embed fused
        }
    } else {
#pragma unroll
        for (int ks = 0; ks < 2; ks++) { short8 z; for (int j = 0; j < 8; j++) z[j] = 0; a[ks] = z; }
    }
    floatx4 acc[8];
#pragma unroll
    for (int nt = 0; nt < 8; nt++) acc[nt] = (floatx4){0.f, 0.f, 0.f, 0.f};
#pragma unroll
    for (int nt = 0; nt < 8; nt++) {
        short8 b0 = *(const short8*)(wb + (size_t)((nt * 2 + 0) * 64 + lane) * 8);
        short8 b1 = *(const short8*)(wb + (size_t)((nt * 2 + 1) * 64 + lane) * 8);
        acc[nt] = __builtin_amdgcn_mfma_f32_16x16x32_bf16(a[0], b0, acc[nt], 0, 0, 0);
        acc[nt] = __builtin_amdgcn_mfma_f32_16x16x32_bf16(a[1], b1, acc[nt], 0, 0, 0);
    }
    float bq[4];
#pragma unroll
    for (int nt = 0; nt < 4; nt++) bq[nt] = bg[nt * 16 + lm];
#pragma unroll
    for (int reg = 0; reg < 4; reg++) {
        int rown = wv * 16 + quad * 4 + reg;
        unsigned char* rb = outs + rown * 272;
#pragma unroll
        for (int nt = 0; nt < 4; nt++)
            rb[nt * 16 + lm] = f32_to_fp8(acc[nt][reg]);
#pragma unroll
        for (int nt = 4; nt < 8; nt++)
            *(__half*)(rb + 64 + (((nt - 4) * 16 + lm) << 1)) = __float2half(acc[nt][reg] + bq[nt - 4]);
    }
    // per-wave store of own 16 rows (same-wave LDS ordering, no barrier)
#pragma unroll
    for (int pass = 0; pass < 3; pass++) {
        int idx = pass * 64 + lane;          // 0..191 = 16 nodes x 12 segs
        int ndl = (idx * 171) >> 11;         // idx/12
        int seg = idx - ndl * 12;
        int rown = wv * 16 + ndl;
        int gn = nbase + rown;
        if (gn < NND) {
            int off = (seg < 4) ? seg * 16 : 64 + (seg - 4) * 16;
            uint4 v = *(const uint4*)(outs + rown * 272 + off);
            if (seg < 4) *(uint4*)(P8 + (size_t)gn * 64 + seg * 16) = v;
            else *(uint4*)((char*)Q16 + (size_t)gn * 128 + (seg - 4) * 16) = v;
        }
    }
}

// ---------------- fused layer: barrier-free wave-owned tiles; fp8 P; (256,4): natural 60 VGPR, no spill ----------------
__global__ __launch_bounds__(256, 4) void k_aggupd(short* __restrict__ x16, const unsigned char* __restrict__ P8,
                                                   const __half* __restrict__ Q16,
                                                   const int* __restrict__ rowb, const int* __restrict__ degv,
                                                   const int* __restrict__ srcs,
                                                   const short* __restrict__ wu, const float* __restrict__ ub,
                                                   const float* __restrict__ lg, const float* __restrict__ lb,
                                                   const short* __restrict__ wm, const float* __restrict__ bgn,
                                                   unsigned char* __restrict__ Pout, __half* __restrict__ Qout,
                                                   float* __restrict__ pscratch, int last) {
    __shared__ float aggs[64 * 68];            // 17408 B; reused as byte-staging (stride 272) in phase 3
    __shared__ float redsum[64];
    __shared__ unsigned redmax[64];
    int t = threadIdx.x, w = t >> 6, lane = t & 63;

    if (last) {
        if (t < 64) redsum[t] = 0.f;
        else if (t < 128) redmax[t - 64] = 0u;
        __syncthreads();
    }

    // ---- phase 1: gather (lane = node w*16+(lane>>2), feats (lane&3)*16..+15; fp8 P) ----
    {
        int ln = lane >> 2, fq = lane & 3, c0 = fq * 16;
        int bn = w * 16 + ln;
        int wid = blockIdx.x * 64 + bn;
        float acc[16];
#pragma unroll
        for (int k = 0; k < 16; k++) acc[k] = 0.f;
        if (wid < NND) {
            int beg = rowb[wid], dg = degv[wid], end = beg + dg;
            float qv[16];
            load_h8(Q16 + (size_t)wid * 64 + c0, qv);
            load_h8(Q16 + (size_t)wid * 64 + c0 + 8, qv + 8);
            int e = beg;
            int n0 = 0, n1 = 0, n2 = 0, n3 = 0;
            if (e + 4 <= end) { n0 = srcs[e]; n1 = srcs[e + 1]; n2 = srcs[e + 2]; n3 = srcs[e + 3]; }
            while (e + 4 <= end) {
                int c0s = n0, c1s = n1, c2s = n2, c3s = n3;
                int en = e + 4;
                if (en + 4 <= end) { n0 = srcs[en]; n1 = srcs[en + 1]; n2 = srcs[en + 2]; n3 = srcs[en + 3]; }
                float f0[16], f1[16], f2[16], f3[16];
                load_f8x16(P8 + (size_t)c0s * 64 + c0, f0);
                load_f8x16(P8 + (size_t)c1s * 64 + c0, f1);
                load_f8x16(P8 + (size_t)c2s * 64 + c0, f2);
                load_f8x16(P8 + (size_t)c3s * 64 + c0, f3);
#pragma unroll
                for (int k = 0; k < 16; k++) {
                    acc[k] += fmaxf(f0[k] + qv[k], 0.f) + fmaxf(f1[k] + qv[k], 0.f);
                    acc[k] += fmaxf(f2[k] + qv[k], 0.f) + fmaxf(f3[k] + qv[k], 0.f);
                }
                e = en;
            }
            for (; e < end; e++) {
                int s = srcs[e];
                float f0[16];
                load_f8x16(P8 + (size_t)s * 64 + c0, f0);
#pragma unroll
                for (int k = 0; k < 16; k++) acc[k] += fmaxf(f0[k] + qv[k], 0.f);
            }
            float inv = 1.f / fmaxf((float)dg, 1.f);
#pragma unroll
            for (int s4 = 0; s4 < 4; s4++)
                *(float4*)(aggs + bn * 68 + c0 + s4 * 4) =
                    make_float4(acc[s4 * 4] * inv, acc[s4 * 4 + 1] * inv,
                                acc[s4 * 4 + 2] * inv, acc[s4 * 4 + 3] * inv);
        } else {
#pragma unroll
            for (int s4 = 0; s4 < 4; s4++)
                *(float4*)(aggs + bn * 68 + c0 + s4 * 4) = make_float4(0.f, 0.f, 0.f, 0.f);
        }
    }
    // no barrier: all LDS deps are same-wave (HW-ordered)

    int lm = lane & 15, quad = lane >> 4;
    int m = blockIdx.x * 64 + w * 16 + lm;
    int bm = w * 16 + lm;

    // ---- phase 2: upd MFMA + LN (own tile) ----
    short8 a[4];
#pragma unroll
    for (int ks = 0; ks < 2; ks++) {
        if (m < NND) a[ks] = *(const short8*)(x16 + (size_t)m * 64 + ks * 32 + quad * 8);
        else { short8 z; for (int j = 0; j < 8; j++) z[j] = 0; a[ks] = z; }
    }
#pragma unroll
    for (int ks = 2; ks < 4; ks++) {
        const float* p = aggs + bm * 68 + (ks - 2) * 32 + quad * 8;
        float4 v0 = *(const float4*)p;
        float4 v1 = *(const float4*)(p + 4);
        float xv[8] = {v0.x, v0.y, v0.z, v0.w, v1.x, v1.y, v1.z, v1.w};
        short8 av;
#pragma unroll
        for (int j = 0; j < 8; j++) av[j] = f2bf(xv[j]);
        a[ks] = av;
    }
    floatx4 acc4[4];
#pragma unroll
    for (int nt = 0; nt < 4; nt++) acc4[nt] = (floatx4){0.f, 0.f, 0.f, 0.f};
#pragma unroll
    for (int nt = 0; nt < 4; nt++) {
#pragma unroll
        for (int ks = 0; ks < 4; ks++) {
            short8 b = *(const short8*)(wu + (size_t)((nt * 4 + ks) * 64 + lane) * 8);
            acc4[nt] = __builtin_amdgcn_mfma_f32_16x16x32_bf16(a[ks], b, acc4[nt], 0, 0, 0);
        }
    }
    float ubv[4], lgv[4], lbv[4];
#pragma unroll
    for (int nt = 0; nt < 4; nt++) {
        int col = nt * 16 + lm;
        ubv[nt] = ub[col]; lgv[nt] = lg[col]; lbv[nt] = lb[col];
    }
    float csum[4] = {0.f, 0.f, 0.f, 0.f};
    float cmax[4] = {-3.402823466e38f, -3.402823466e38f, -3.402823466e38f, -3.402823466e38f};
#pragma unroll
    for (int reg = 0; reg < 4; reg++) {
        int rown = w * 16 + quad * 4 + reg;
        int gn = blockIdx.x * 64 + rown;
        bool ok = gn < NND;
        float h[4];
#pragma unroll
        for (int nt = 0; nt < 4; nt++) {
            float xv = ok ? bf2f(x16[(size_t)gn * 64 + nt * 16 + lm]) : 0.f;
            float u = fmaxf(acc4[nt][reg] + ubv[nt], 0.f);
            h[nt] = u + xv;
        }
        float s1 = h[0] + h[1] + h[2] + h[3];
        float s2 = h[0] * h[0] + h[1] * h[1] + h[2] * h[2] + h[3] * h[3];
#pragma unroll
        for (int off = 1; off < 16; off *= 2) {
            s1 += __shfl_xor(s1, off);
            s2 += __shfl_xor(s2, off);
        }
        float mu = s1 * (1.f / 64.f);
        float var = s2 * (1.f / 64.f) - mu * mu;
        float rs = rsqrtf(var + LNEPS);
#pragma unroll
        for (int nt = 0; nt < 4; nt++) {
            float res = (h[nt] - mu) * rs * lgv[nt] + lbv[nt];
            if (!last) {
                if (ok) x16[(size_t)gn * 64 + nt * 16 + lm] = f2bf(res);
                aggs[rown * 68 + nt * 16 + lm] = res;   // new-x for phase 3 (own tile rows)
            } else if (ok) {
                csum[nt] += res;
                cmax[nt] = fmaxf(cmax[nt], res);
            }
        }
    }

    if (last) {
        // ---- folded final reduce: quad-combine, LDS stage, NON-ATOMIC per-block partials ----
#pragma unroll
        for (int nt = 0; nt < 4; nt++) {
            csum[nt] += __shfl_xor(csum[nt], 16);
            csum[nt] += __shfl_xor(csum[nt], 32);
            cmax[nt] = fmaxf(cmax[nt], __shfl_xor(cmax[nt], 16));
            cmax[nt] = fmaxf(cmax[nt], __shfl_xor(cmax[nt], 32));
        }
        if (quad == 0) {
#pragma unroll
            for (int nt = 0; nt < 4; nt++) {
                atomicAdd(&redsum[nt * 16 + lm], csum[nt]);
                unsigned b = __float_as_uint(cmax[nt]);
                unsigned enc = (b & 0x80000000u) ? ~b : (b | 0x80000000u);
                atomicMax(&redmax[nt * 16 + lm], enc);
            }
        }
        __syncthreads();
        float* ps = pscratch + (size_t)blockIdx.x * 128;
        if (t < 64) {
            ps[t] = redsum[t];
        } else if (t < 128) {
            unsigned u = redmax[t - 64];
            unsigned b = (u & 0x80000000u) ? (u & 0x7fffffffu) : ~u;
            ps[t] = __uint_as_float(b);
        }
        return;
    }

    // ---- phase 3: next-layer P(fp8)/Q(fp16) for own tile (same wave, no barrier) ----
    {
        unsigned char* bs = (unsigned char*)aggs;    // byte view, row stride 272
        short8 na[2];
#pragma unroll
        for (int ks = 0; ks < 2; ks++) {
            const float* p = aggs + bm * 68 + ks * 32 + quad * 8;
            float4 v0 = *(const float4*)p;
            float4 v1 = *(const float4*)(p + 4);
            float xv[8] = {v0.x, v0.y, v0.z, v0.w, v1.x, v1.y, v1.z, v1.w};
            short8 av;
#pragma unroll
            for (int j = 0; j < 8; j++) av[j] = f2bf(xv[j]);
            na[ks] = av;
        }
        floatx4 c8[8];
#pragma unroll
        for (int nt = 0; nt < 8; nt++) c8[nt] = (floatx4){0.f, 0.f, 0.f, 0.f};
#pragma unroll
        for (int nt = 0; nt < 8; nt++) {
            short8 b0 = *(const short8*)(wm + (size_t)((nt * 2 + 0) * 64 + lane) * 8);
            short8 b1 = *(const short8*)(wm + (size_t)((nt * 2 + 1) * 64 + lane) * 8);
            c8[nt] = __builtin_amdgcn_mfma_f32_16x16x32_bf16(na[0], b0, c8[nt], 0, 0, 0);
            c8[nt] = __builtin_amdgcn_mfma_f32_16x16x32_bf16(na[1], b1, c8[nt], 0, 0, 0);
        }
        float bq[4];
#pragma unroll
        for (int nt = 0; nt < 4; nt++) bq[nt] = bgn[nt * 16 + lm];
#pragma unroll
        for (int reg = 0; reg < 4; reg++) {
            int rown = w * 16 + quad * 4 + reg;
            unsigned char* rb = bs + rown * 272;
#pragma unroll
            for (int nt = 0; nt < 4; nt++)
                rb[nt * 16 + lm] = f32_to_fp8(c8[nt][reg]);
#pragma unroll
            for (int nt = 4; nt < 8; nt++)
                *(__half*)(rb + 64 + (((nt - 4) * 16 + lm) << 1)) = __float2half(c8[nt][reg] + bq[nt - 4]);
        }
#pragma unroll
        for (int pass = 0; pass < 3; pass++) {
            int idx = pass * 64 + lane;          // 0..191 = 16 nodes x 12 segs
            int ndl = (idx * 171) >> 11;         // idx/12
            int seg = idx - ndl * 12;
            int rown = w * 16 + ndl;
            int gn = blockIdx.x * 64 + rown;
            if (gn < NND) {
                int off = (seg < 4) ? seg * 16 : 64 + (seg - 4) * 16;
                uint4 v = *(const uint4*)(bs + rown * 272 + off);
                if (seg < 4) *(uint4*)(Pout + (size_t)gn * 64 + seg * 16) = v;
                else *(uint4*)((char*)Qout + (size_t)gn * 128 + (seg - 4) * 16) = v;
            }
        }
    }
}

// ---------------- final: 128 blocks, block c reduces column c over GB block-partials ----------------
__global__ __launch_bounds__(256) void k_fin(const float* __restrict__ pscratch, float* __restrict__ out) {
    __shared__ float sm[256];
    int b = blockIdx.x;      // 0..127: 0-63 sum columns, 64-127 max columns
    int t = threadIdx.x;
    bool issum = b < 64;
    float v = issum ? 0.f : -3.402823466e38f;
    for (int i = t; i < GB; i += 256) {
        float x = pscratch[(size_t)i * 128 + b];
        v = issum ? (v + x) : fmaxf(v, x);
    }
    sm[t] = v; __syncthreads();
    for (int off = 128; off > 0; off >>= 1) {
        if (t < off) sm[t] = issum ? (sm[t] + sm[t + off]) : fmaxf(sm[t], sm[t + off]);
        __syncthreads();
    }
    if (t == 0) out[b] = issum ? sm[0] * (1.f / (float)NND) : sm[0];
}

extern "C" void kernel_launch(void* const* d_in, const int* in_sizes, int n_in,
                              void* d_out, int out_size, void* d_ws, size_t ws_size,
                              hipStream_t stream) {
    const int* ty      = (const int*)d_in[0];
    const int* ed      = (const int*)d_in[1];
    const float* tab   = (const float*)d_in[2];
    const float* msg_w = (const float*)d_in[3];
    const float* msg_b = (const float*)d_in[4];
    const float* upd_w = (const float*)d_in[5];
    const float* upd_b = (const float*)d_in[6];
    const float* ln_g  = (const float*)d_in[7];
    const float* ln_b  = (const float*)d_in[8];
    float* out = (float*)d_out;

    char* w = (char*)d_ws;
    auto alloc = [&](size_t sz) { char* p = w; w += (sz + 255) & ~(size_t)255; return p; };
    short* x16         = (short*)alloc((size_t)NND * 64 * 2);
    unsigned char* P0  = (unsigned char*)alloc((size_t)NND * 64);
    unsigned char* P1  = (unsigned char*)alloc((size_t)NND * 64);
    __half* Q0         = (__half*)alloc((size_t)NND * 64 * 2);
    __half* Q1         = (__half*)alloc((size_t)NND * 64 * 2);
    long long* tmp     = (long long*)alloc((size_t)NBKT * CAP * 8);
    int* srcs          = (int*)alloc((size_t)NBKT * CAP * 4);
    int* rowb          = (int*)alloc((size_t)NND * 4);
    int* degv          = (int*)alloc((size_t)NND * 4);
    int* gtail         = (int*)alloc(256 * 4);
    float* pscratch    = (float*)alloc((size_t)GB * 128 * 4);
    short* wmsg        = (short*)alloc((size_t)NLAY * 8192 * 2);
    short* wupd        = (short*)alloc((size_t)NLAY * 8192 * 2);

    k_init<<<1, 256, 0, stream>>>(gtail);
    k_prep<<<(2 * NLAY * 8192 + 255) / 256, 256, 0, stream>>>(msg_w, upd_w, wmsg, wupd);
    k_bscatter<<<(NED + 2047) / 2048, 256, 0, stream>>>((const int2*)ed, gtail, tmp);
    k_bfinish<<<NBKT, 512, 0, stream>>>(tmp, gtail, rowb, degv, srcs);

    k_pq<<<GB, 256, 0, stream>>>(ty, tab, wmsg, msg_b, P0, Q0, x16);

    k_aggupd<<<GB, 256, 0, stream>>>(x16, P0, Q0, rowb, degv, srcs,
                                     wupd + 0 * 8192, upd_b + 0, ln_g + 0, ln_b + 0,
                                     wmsg + 1 * 8192, msg_b + 64, P1, Q1, pscratch, 0);
    k_aggupd<<<GB, 256, 0, stream>>>(x16, P1, Q1, rowb, degv, srcs,
                                     wupd + 1 * 8192, upd_b + 64, ln_g + 64, ln_b + 64,
                                     wmsg + 2 * 8192, msg_b + 128, P0, Q0, pscratch, 0);
    k_aggupd<<<GB, 256, 0, stream>>>(x16, P0, Q0, rowb, degv, srcs,
                                     wupd + 2 * 8192, upd_b + 128, ln_g + 128, ln_b + 128,
                                     wmsg + 2 * 8192, msg_b + 128, P1, Q1, pscratch, 1);

    k_fin<<<128, 256, 0, stream>>>(pscratch, out);
}

// Round 18
// 220.261 us; speedup vs baseline: 1.8364x; 1.0294x over previous
//
#include <hip/hip_runtime.h>
#include <hip/hip_fp16.h>
#include <math.h>

#define NND 100000
#define NED 800000
#define NLAY 3
#define BSH 9                      // 512 nodes per bucket
#define NBKT ((NND + 511) / 512)   // 196
#define CAP 8192                   // slack edge capacity per bucket (mean 4096, sigma 64)
#define GB  ((NND + 63) / 64)      // 1563 layer blocks
static constexpr float LNEPS = 1e-5f;

typedef __attribute__((ext_vector_type(8))) short short8;
typedef __attribute__((ext_vector_type(4))) float floatx4;
typedef __attribute__((ext_vector_type(2))) float floatx2;

// fp32 -> bf16 round-to-nearest-even
__device__ __forceinline__ short f2bf(float f) {
    unsigned u = __float_as_uint(f);
    u += 0x7fffu + ((u >> 16) & 1u);
    return (short)(u >> 16);
}
__device__ __forceinline__ float bf2f(short s) {
    return __uint_as_float(((unsigned)(unsigned short)s) << 16);
}

// unpack 8 consecutive halfs (16B) into fp32
__device__ __forceinline__ void load_h8(const __half* p, float* f) {
    uint4 v = *(const uint4*)p;
    unsigned a[4] = {v.x, v.y, v.z, v.w};
#pragma unroll
    for (int k = 0; k < 4; k++) {
        __half2 h = *(__half2*)&a[k];
        float2 g = __half22float2(h);
        f[2 * k] = g.x; f[2 * k + 1] = g.y;
    }
}

// unpack 16 fp8 e4m3 (packed uint4) into fp32 via HW pk-cvt
__device__ __forceinline__ void unpack_f8x16(uint4 v, float* f) {
    unsigned a[4] = {v.x, v.y, v.z, v.w};
#pragma unroll
    for (int k = 0; k < 4; k++) {
        floatx2 lo = __builtin_amdgcn_cvt_pk_f32_fp8(a[k], false);
        floatx2 hi = __builtin_amdgcn_cvt_pk_f32_fp8(a[k], true);
        f[4 * k + 0] = lo[0]; f[4 * k + 1] = lo[1];
        f[4 * k + 2] = hi[0]; f[4 * k + 3] = hi[1];
    }
}
__device__ __forceinline__ unsigned char f32_to_fp8(float v) {
    int r = __builtin_amdgcn_cvt_pk_fp8_f32(v, v, 0, false);
    return (unsigned char)(r & 0xff);
}

// ---------------- init: bucket tails to slack bases ----------------
__global__ void k_init(int* __restrict__ gtail) {
    int gt = blockIdx.x * blockDim.x + threadIdx.x;
    if (gt < NBKT) gtail[gt] = gt * CAP;
}

// ---------------- bin edges by bucket into slack-capacity tmp (packed tgt<<32|src) ----------------
__global__ __launch_bounds__(256) void k_bscatter(const int2* __restrict__ e, int* __restrict__ gtail,
                                                  long long* __restrict__ tmp) {
    __shared__ int cnt[NBKT], chunk[NBKT], cur[NBKT];
    const int T = 2048;
    int ntile = (NED + T - 1) / T;
    for (int tile = blockIdx.x; tile < ntile; tile += gridDim.x) {
        int base = tile * T;
        int t = threadIdx.x;
        for (int i = t; i < NBKT; i += 256) { cnt[i] = 0; cur[i] = 0; }
        __syncthreads();
        int2 ed[8]; int bk[8];
#pragma unroll
        for (int i = 0; i < 8; i++) {
            int idx = base + i * 256 + t;
            if (idx < NED) {
                ed[i] = e[idx];
                bk[i] = ((unsigned)ed[i].y) >> BSH;
                atomicAdd(&cnt[bk[i]], 1);
            } else bk[i] = -1;
        }
        __syncthreads();
        for (int i = t; i < NBKT; i += 256) if (cnt[i]) chunk[i] = atomicAdd(&gtail[i], cnt[i]);
        __syncthreads();
#pragma unroll
        for (int i = 0; i < 8; i++) {
            if (bk[i] >= 0) {
                int r = atomicAdd(&cur[bk[i]], 1);
                tmp[(size_t)chunk[bk[i]] + r] =
                    ((long long)(unsigned)ed[i].y << 32) | (unsigned)ed[i].x;
            }
        }
        __syncthreads();
    }
}

// ---------------- per-bucket CSR finish: rowb (begin) + degv (degree) + srcs ----------------
__global__ __launch_bounds__(512) void k_bfinish(const long long* __restrict__ tmp, const int* __restrict__ gtail,
                                                 int* __restrict__ rowb, int* __restrict__ degv,
                                                 int* __restrict__ srcs) {
    __shared__ int ld[512];
    __shared__ int lcur[512];
    int b = blockIdx.x, t = threadIdx.x;
    int node0 = b << BSH;
    int nn = min(512, NND - node0);
    int ebase = b * CAP, eend = gtail[b];
    ld[t] = 0;
    __syncthreads();
    for (int i = ebase + t; i < eend; i += 512) {
        int tgt = (int)(tmp[i] >> 32);
        atomicAdd(&ld[tgt - node0], 1);
    }
    __syncthreads();
    int v = ld[t];
    for (int off = 1; off < 512; off <<= 1) {
        int u = (t >= off) ? ld[t - off] : 0;
        __syncthreads();
        ld[t] += u;
        __syncthreads();
    }
    int exc = ld[t] - v;
    if (t < nn) { rowb[node0 + t] = ebase + exc; degv[node0 + t] = v; }
    lcur[t] = exc;
    __syncthreads();
    for (int i = ebase + t; i < eend; i += 512) {
        long long pk = tmp[i];
        int tgt = (int)(pk >> 32);
        int src = (int)(pk & 0xffffffffll);
        int p = atomicAdd(&lcur[tgt - node0], 1);
        srcs[ebase + p] = src;
    }
}

// ---------------- prep: pre-swizzle weights into MFMA B-fragment layout (bf16) ----------------
__global__ void k_prep(const float* __restrict__ msg_w, const float* __restrict__ upd_w,
                       short* __restrict__ wmsg, short* __restrict__ wupd) {
    int t = blockIdx.x * blockDim.x + threadIdx.x;
    if (t >= 2 * NLAY * 8192) return;
    int which = t / (NLAY * 8192);
    int e = t % (NLAY * 8192);
    int l = e >> 13, idx = e & 8191;
    int j = idx & 7, lane = (idx >> 3) & 63, hi = idx >> 9;
    int lm = lane & 15, quad = lane >> 4;
    if (which == 0) {
        int ks = hi & 1, nt = hi >> 1;
        int n = nt * 16 + lm, k = ks * 32 + quad * 8 + j;
        float v = (n < 64) ? msg_w[(size_t)l * 8192 + k * 64 + n]
                           : msg_w[(size_t)l * 8192 + (64 + k) * 64 + (n - 64)];
        wmsg[e] = f2bf(v);
    } else {
        int ks = hi & 3, nt = hi >> 2;
        int n = nt * 16 + lm, k = ks * 32 + quad * 8 + j;
        wupd[e] = f2bf(upd_w[(size_t)l * 8192 + k * 64 + n]);
    }
}

// ---------------- layer-0 P(fp8)/Q(fp16) + embed fused, per-wave staging (barrier-free) ----------------
__global__ __launch_bounds__(256) void k_pq(const int* __restrict__ ty, const float* __restrict__ tab,
                                            const short* __restrict__ wb, const float* __restrict__ bg,
                                            unsigned char* __restrict__ P8, __half* __restrict__ Q16,
                                            short* __restrict__ x16) {
    __shared__ unsigned char outs[64 * 272];   // per node: 64B P fp8 | 128B Q half | 80B pad
    int wv = threadIdx.x >> 6, lane = threadIdx.x & 63;
    int lm = lane & 15, quad = lane >> 4;
    int nbase = blockIdx.x * 64;
    int m = nbase + wv * 16 + lm;
    short8 a[2];
    if (m < NND) {
        const float* tr = tab + ty[m] * 64;
#pragma unroll
        for (int ks = 0; ks < 2; ks++) {
            float4 v0 = *(const float4*)(tr + ks * 32 + quad * 8);
            float4 v1 = *(const float4*)(tr + ks * 32 + quad * 8 + 4);
            short8 av;
            av[0] = f2bf(v0.x); av[1] = f2bf(v0.y); av[2] = f2bf(v0.z); av[3] = f2bf(v0.w);
            av[4] = f2bf(v1.x); av[5] = f2bf(v1.y); av[6] = f2bf(v1.z); av[7] = f2bf(v1.w);
            a[ks] = av;
            *(short8*)(x16 + (size_t)m * 64 + ks * 32 + quad * 8) = av;   // embed fused
        }
    } else {
#pragma unroll
        for (int ks = 0; ks < 2; ks++) { short8 z; for (int j = 0; j < 8; j++) z[j] = 0; a[ks] = z; }
    }
    floatx4 acc[8];
#pragma unroll
    for (int nt = 0; nt < 8; nt++) acc[nt] = (floatx4){0.f, 0.f, 0.f, 0.f};
#pragma unroll
    for (int nt = 0; nt < 8; nt++) {
        short8 b0 = *(const short8*)(wb + (size_t)((nt * 2 + 0) * 64 + lane) * 8);
        short8 b1 = *(const short8*)(wb + (size_t)((nt * 2 + 1) * 64 + lane) * 8);
        acc[nt] = __builtin_amdgcn_mfma_f32_16x16x32_bf16(a[0], b0, acc[nt], 0, 0, 0);
        acc[nt] = __builtin_amdgcn_mfma_f32_16x16x32_bf16(a[1], b1, acc[nt], 0, 0, 0);
    }
    float bq[4];
#pragma unroll
    for (int nt = 0; nt < 4; nt++) bq[nt] = bg[nt * 16 + lm];
#pragma unroll
    for (int reg = 0; reg < 4; reg++) {
        int rown = wv * 16 + quad * 4 + reg;
        unsigned char* rb = outs + rown * 272;
#pragma unroll
        for (int nt = 0; nt < 4; nt++)
            rb[nt * 16 + lm] = f32_to_fp8(acc[nt][reg]);
#pragma unroll
        for (int nt = 4; nt < 8; nt++)
            *(__half*)(rb + 64 + (((nt - 4) * 16 + lm) << 1)) = __float2half(acc[nt][reg] + bq[nt - 4]);
    }
    // per-wave store of own 16 rows (same-wave LDS ordering, no barrier)
#pragma unroll
    for (int pass = 0; pass < 3; pass++) {
        int idx = pass * 64 + lane;          // 0..191 = 16 nodes x 12 segs
        int ndl = (idx * 171) >> 11;         // idx/12
        int seg = idx - ndl * 12;
        int rown = wv * 16 + ndl;
        int gn = nbase + rown;
        if (gn < NND) {
            int off = (seg < 4) ? seg * 16 : 64 + (seg - 4) * 16;
            uint4 v = *(const uint4*)(outs + rown * 272 + off);
            if (seg < 4) *(uint4*)(P8 + (size_t)gn * 64 + seg * 16) = v;
            else *(uint4*)((char*)Q16 + (size_t)gn * 128 + (seg - 4) * 16) = v;
        }
    }
}

// ---------------- fused layer: barrier-free wave-owned tiles; fp8 P; 8-wide predicated gather ----------------
__global__ __launch_bounds__(256, 4) void k_aggupd(short* __restrict__ x16, const unsigned char* __restrict__ P8,
                                                   const __half* __restrict__ Q16,
                                                   const int* __restrict__ rowb, const int* __restrict__ degv,
                                                   const int* __restrict__ srcs,
                                                   const short* __restrict__ wu, const float* __restrict__ ub,
                                                   const float* __restrict__ lg, const float* __restrict__ lb,
                                                   const short* __restrict__ wm, const float* __restrict__ bgn,
                                                   unsigned char* __restrict__ Pout, __half* __restrict__ Qout,
                                                   float* __restrict__ pscratch, int last) {
    __shared__ float aggs[64 * 68];            // 17408 B; reused as byte-staging (stride 272) in phase 3
    __shared__ float redsum[64];
    __shared__ unsigned redmax[64];
    int t = threadIdx.x, w = t >> 6, lane = t & 63;

    if (last) {
        if (t < 64) redsum[t] = 0.f;
        else if (t < 128) redmax[t - 64] = 0u;
        __syncthreads();
    }

    // ---- phase 1: gather (lane = node w*16+(lane>>2), feats (lane&3)*16..+15; fp8 P) ----
    // 8-wide predicated batch: all loads issue unconditionally (index clamped), tail masked.
    {
        int ln = lane >> 2, fq = lane & 3, c0 = fq * 16;
        int bn = w * 16 + ln;
        int wid = blockIdx.x * 64 + bn;
        float acc[16];
#pragma unroll
        for (int k = 0; k < 16; k++) acc[k] = 0.f;
        if (wid < NND) {
            int beg = rowb[wid], dg = degv[wid], end = beg + dg;
            float qv[16];
            load_h8(Q16 + (size_t)wid * 64 + c0, qv);
            load_h8(Q16 + (size_t)wid * 64 + c0 + 8, qv + 8);
            for (int e = beg; e < end; e += 8) {
                int last_e = end - 1;
                int s[8];
#pragma unroll
                for (int i = 0; i < 8; i++) {
                    int ei = e + i;
                    s[i] = srcs[ei < end ? ei : last_e];
                }
                uint4 pk[8];
#pragma unroll
                for (int i = 0; i < 8; i++)
                    pk[i] = *(const uint4*)(P8 + (size_t)s[i] * 64 + c0);
#pragma unroll
                for (int i = 0; i < 8; i++) {
                    if (e + i < end) {
                        float f[16];
                        unpack_f8x16(pk[i], f);
#pragma unroll
                        for (int k = 0; k < 16; k++) acc[k] += fmaxf(f[k] + qv[k], 0.f);
                    }
                }
            }
            float inv = 1.f / fmaxf((float)dg, 1.f);
#pragma unroll
            for (int s4 = 0; s4 < 4; s4++)
                *(float4*)(aggs + bn * 68 + c0 + s4 * 4) =
                    make_float4(acc[s4 * 4] * inv, acc[s4 * 4 + 1] * inv,
                                acc[s4 * 4 + 2] * inv, acc[s4 * 4 + 3] * inv);
        } else {
#pragma unroll
            for (int s4 = 0; s4 < 4; s4++)
                *(float4*)(aggs + bn * 68 + c0 + s4 * 4) = make_float4(0.f, 0.f, 0.f, 0.f);
        }
    }
    // no barrier: all LDS deps are same-wave (HW-ordered)

    int lm = lane & 15, quad = lane >> 4;
    int m = blockIdx.x * 64 + w * 16 + lm;
    int bm = w * 16 + lm;

    // ---- phase 2: upd MFMA + LN (own tile) ----
    short8 a[4];
#pragma unroll
    for (int ks = 0; ks < 2; ks++) {
        if (m < NND) a[ks] = *(const short8*)(x16 + (size_t)m * 64 + ks * 32 + quad * 8);
        else { short8 z; for (int j = 0; j < 8; j++) z[j] = 0; a[ks] = z; }
    }
#pragma unroll
    for (int ks = 2; ks < 4; ks++) {
        const float* p = aggs + bm * 68 + (ks - 2) * 32 + quad * 8;
        float4 v0 = *(const float4*)p;
        float4 v1 = *(const float4*)(p + 4);
        float xv[8] = {v0.x, v0.y, v0.z, v0.w, v1.x, v1.y, v1.z, v1.w};
        short8 av;
#pragma unroll
        for (int j = 0; j < 8; j++) av[j] = f2bf(xv[j]);
        a[ks] = av;
    }
    floatx4 acc4[4];
#pragma unroll
    for (int nt = 0; nt < 4; nt++) acc4[nt] = (floatx4){0.f, 0.f, 0.f, 0.f};
#pragma unroll
    for (int nt = 0; nt < 4; nt++) {
#pragma unroll
        for (int ks = 0; ks < 4; ks++) {
            short8 b = *(const short8*)(wu + (size_t)((nt * 4 + ks) * 64 + lane) * 8);
            acc4[nt] = __builtin_amdgcn_mfma_f32_16x16x32_bf16(a[ks], b, acc4[nt], 0, 0, 0);
        }
    }
    float ubv[4], lgv[4], lbv[4];
#pragma unroll
    for (int nt = 0; nt < 4; nt++) {
        int col = nt * 16 + lm;
        ubv[nt] = ub[col]; lgv[nt] = lg[col]; lbv[nt] = lb[col];
    }
    float csum[4] = {0.f, 0.f, 0.f, 0.f};
    float cmax[4] = {-3.402823466e38f, -3.402823466e38f, -3.402823466e38f, -3.402823466e38f};
#pragma unroll
    for (int reg = 0; reg < 4; reg++) {
        int rown = w * 16 + quad * 4 + reg;
        int gn = blockIdx.x * 64 + rown;
        bool ok = gn < NND;
        float h[4];
#pragma unroll
        for (int nt = 0; nt < 4; nt++) {
            float xv = ok ? bf2f(x16[(size_t)gn * 64 + nt * 16 + lm]) : 0.f;
            float u = fmaxf(acc4[nt][reg] + ubv[nt], 0.f);
            h[nt] = u + xv;
        }
        float s1 = h[0] + h[1] + h[2] + h[3];
        float s2 = h[0] * h[0] + h[1] * h[1] + h[2] * h[2] + h[3] * h[3];
#pragma unroll
        for (int off = 1; off < 16; off *= 2) {
            s1 += __shfl_xor(s1, off);
            s2 += __shfl_xor(s2, off);
        }
        float mu = s1 * (1.f / 64.f);
        float var = s2 * (1.f / 64.f) - mu * mu;
        float rs = rsqrtf(var + LNEPS);
#pragma unroll
        for (int nt = 0; nt < 4; nt++) {
            float res = (h[nt] - mu) * rs * lgv[nt] + lbv[nt];
            if (!last) {
                if (ok) x16[(size_t)gn * 64 + nt * 16 + lm] = f2bf(res);
                aggs[rown * 68 + nt * 16 + lm] = res;   // new-x for phase 3 (own tile rows)
            } else if (ok) {
                csum[nt] += res;
                cmax[nt] = fmaxf(cmax[nt], res);
            }
        }
    }

    if (last) {
        // ---- folded final reduce: quad-combine, LDS stage, NON-ATOMIC per-block partials ----
#pragma unroll
        for (int nt = 0; nt < 4; nt++) {
            csum[nt] += __shfl_xor(csum[nt], 16);
            csum[nt] += __shfl_xor(csum[nt], 32);
            cmax[nt] = fmaxf(cmax[nt], __shfl_xor(cmax[nt], 16));
            cmax[nt] = fmaxf(cmax[nt], __shfl_xor(cmax[nt], 32));
        }
        if (quad == 0) {
#pragma unroll
            for (int nt = 0; nt < 4; nt++) {
                atomicAdd(&redsum[nt * 16 + lm], csum[nt]);
                unsigned b = __float_as_uint(cmax[nt]);
                unsigned enc = (b & 0x80000000u) ? ~b : (b | 0x80000000u);
                atomicMax(&redmax[nt * 16 + lm], enc);
            }
        }
        __syncthreads();
        float* ps = pscratch + (size_t)blockIdx.x * 128;
        if (t < 64) {
            ps[t] = redsum[t];
        } else if (t < 128) {
            unsigned u = redmax[t - 64];
            unsigned b = (u & 0x80000000u) ? (u & 0x7fffffffu) : ~u;
            ps[t] = __uint_as_float(b);
        }
        return;
    }

    // ---- phase 3: next-layer P(fp8)/Q(fp16) for own tile (same wave, no barrier) ----
    {
        unsigned char* bs = (unsigned char*)aggs;    // byte view, row stride 272
        short8 na[2];
#pragma unroll
        for (int ks = 0; ks < 2; ks++) {
            const float* p = aggs + bm * 68 + ks * 32 + quad * 8;
            float4 v0 = *(const float4*)p;
            float4 v1 = *(const float4*)(p + 4);
            float xv[8] = {v0.x, v0.y, v0.z, v0.w, v1.x, v1.y, v1.z, v1.w};
            short8 av;
#pragma unroll
            for (int j = 0; j < 8; j++) av[j] = f2bf(xv[j]);
            na[ks] = av;
        }
        floatx4 c8[8];
#pragma unroll
        for (int nt = 0; nt < 8; nt++) c8[nt] = (floatx4){0.f, 0.f, 0.f, 0.f};
#pragma unroll
        for (int nt = 0; nt < 8; nt++) {
            short8 b0 = *(const short8*)(wm + (size_t)((nt * 2 + 0) * 64 + lane) * 8);
            short8 b1 = *(const short8*)(wm + (size_t)((nt * 2 + 1) * 64 + lane) * 8);
            c8[nt] = __builtin_amdgcn_mfma_f32_16x16x32_bf16(na[0], b0, c8[nt], 0, 0, 0);
            c8[nt] = __builtin_amdgcn_mfma_f32_16x16x32_bf16(na[1], b1, c8[nt], 0, 0, 0);
        }
        float bq[4];
#pragma unroll
        for (int nt = 0; nt < 4; nt++) bq[nt] = bgn[nt * 16 + lm];
#pragma unroll
        for (int reg = 0; reg < 4; reg++) {
            int rown = w * 16 + quad * 4 + reg;
            unsigned char* rb = bs + rown * 272;
#pragma unroll
            for (int nt = 0; nt < 4; nt++)
                rb[nt * 16 + lm] = f32_to_fp8(c8[nt][reg]);
#pragma unroll
            for (int nt = 4; nt < 8; nt++)
                *(__half*)(rb + 64 + (((nt - 4) * 16 + lm) << 1)) = __float2half(c8[nt][reg] + bq[nt - 4]);
        }
#pragma unroll
        for (int pass = 0; pass < 3; pass++) {
            int idx = pass * 64 + lane;          // 0..191 = 16 nodes x 12 segs
            int ndl = (idx * 171) >> 11;         // idx/12
            int seg = idx - ndl * 12;
            int rown = w * 16 + ndl;
            int gn = blockIdx.x * 64 + rown;
            if (gn < NND) {
                int off = (seg < 4) ? seg * 16 : 64 + (seg - 4) * 16;
                uint4 v = *(const uint4*)(bs + rown * 272 + off);
                if (seg < 4) *(uint4*)(Pout + (size_t)gn * 64 + seg * 16) = v;
                else *(uint4*)((char*)Qout + (size_t)gn * 128 + (seg - 4) * 16) = v;
            }
        }
    }
}

// ---------------- final: 128 blocks, block c reduces column c over GB block-partials ----------------
__global__ __launch_bounds__(256) void k_fin(const float* __restrict__ pscratch, float* __restrict__ out) {
    __shared__ float sm[256];
    int b = blockIdx.x;      // 0..127: 0-63 sum columns, 64-127 max columns
    int t = threadIdx.x;
    bool issum = b < 64;
    float v = issum ? 0.f : -3.402823466e38f;
    for (int i = t; i < GB; i += 256) {
        float x = pscratch[(size_t)i * 128 + b];
        v = issum ? (v + x) : fmaxf(v, x);
    }
    sm[t] = v; __syncthreads();
    for (int off = 128; off > 0; off >>= 1) {
        if (t < off) sm[t] = issum ? (sm[t] + sm[t + off]) : fmaxf(sm[t], sm[t + off]);
        __syncthreads();
    }
    if (t == 0) out[b] = issum ? sm[0] * (1.f / (float)NND) : sm[0];
}

extern "C" void kernel_launch(void* const* d_in, const int* in_sizes, int n_in,
                              void* d_out, int out_size, void* d_ws, size_t ws_size,
                              hipStream_t stream) {
    const int* ty      = (const int*)d_in[0];
    const int* ed      = (const int*)d_in[1];
    const float* tab   = (const float*)d_in[2];
    const float* msg_w = (const float*)d_in[3];
    const float* msg_b = (const float*)d_in[4];
    const float* upd_w = (const float*)d_in[5];
    const float* upd_b = (const float*)d_in[6];
    const float* ln_g  = (const float*)d_in[7];
    const float* ln_b  = (const float*)d_in[8];
    float* out = (float*)d_out;

    char* w = (char*)d_ws;
    auto alloc = [&](size_t sz) { char* p = w; w += (sz + 255) & ~(size_t)255; return p; };
    short* x16         = (short*)alloc((size_t)NND * 64 * 2);
    unsigned char* P0  = (unsigned char*)alloc((size_t)NND * 64);
    unsigned char* P1  = (unsigned char*)alloc((size_t)NND * 64);
    __half* Q0         = (__half*)alloc((size_t)NND * 64 * 2);
    __half* Q1         = (__half*)alloc((size_t)NND * 64 * 2);
    long long* tmp     = (long long*)alloc((size_t)NBKT * CAP * 8);
    int* srcs          = (int*)alloc((size_t)NBKT * CAP * 4);
    int* rowb          = (int*)alloc((size_t)NND * 4);
    int* degv          = (int*)alloc((size_t)NND * 4);
    int* gtail         = (int*)alloc(256 * 4);
    float* pscratch    = (float*)alloc((size_t)GB * 128 * 4);
    short* wmsg        = (short*)alloc((size_t)NLAY * 8192 * 2);
    short* wupd        = (short*)alloc((size_t)NLAY * 8192 * 2);

    k_init<<<1, 256, 0, stream>>>(gtail);
    k_prep<<<(2 * NLAY * 8192 + 255) / 256, 256, 0, stream>>>(msg_w, upd_w, wmsg, wupd);
    k_bscatter<<<(NED + 2047) / 2048, 256, 0, stream>>>((const int2*)ed, gtail, tmp);
    k_bfinish<<<NBKT, 512, 0, stream>>>(tmp, gtail, rowb, degv, srcs);

    k_pq<<<GB, 256, 0, stream>>>(ty, tab, wmsg, msg_b, P0, Q0, x16);

    k_aggupd<<<GB, 256, 0, stream>>>(x16, P0, Q0, rowb, degv, srcs,
                                     wupd + 0 * 8192, upd_b + 0, ln_g + 0, ln_b + 0,
                                     wmsg + 1 * 8192, msg_b + 64, P1, Q1, pscratch, 0);
    k_aggupd<<<GB, 256, 0, stream>>>(x16, P1, Q1, rowb, degv, srcs,
                                     wupd + 1 * 8192, upd_b + 64, ln_g + 64, ln_b + 64,
                                     wmsg + 2 * 8192, msg_b + 128, P0, Q0, pscratch, 0);
    k_aggupd<<<GB, 256, 0, stream>>>(x16, P0, Q0, rowb, degv, srcs,
                                     wupd + 2 * 8192, upd_b + 128, ln_g + 128, ln_b + 128,
                                     wmsg + 2 * 8192, msg_b + 128, P1, Q1, pscratch, 1);

    k_fin<<<128, 256, 0, stream>>>(pscratch, out);
}